// Round 2
// baseline (721.341 us; speedup 1.0000x reference)
//
#include <hip/hip_runtime.h>
#include <math.h>

#define IN_DIM 128
#define HID_DIM 128
#define OUT_DIM 64

// ---------------- init ----------------
__global__ __launch_bounds__(256) void zero_init_kernel(int* __restrict__ counts,
                                                        int* __restrict__ fill,
                                                        float* __restrict__ out, int n) {
    int i = blockIdx.x * 256 + threadIdx.x;
    if (i < n) { counts[i] = 0; fill[i] = 0; }
    if (i < OUT_DIM) out[i] = 0.0f;
}

// ---------------- degree ----------------
__global__ __launch_bounds__(256) void degree_kernel(const int* __restrict__ dst,
                                                     int* __restrict__ counts, int E) {
    int e = blockIdx.x * 256 + threadIdx.x;
    if (e < E) atomicAdd(&counts[dst[e]], 1);
}

__global__ __launch_bounds__(256) void dinv_kernel(const int* __restrict__ counts,
                                                   float* __restrict__ dinv, int n) {
    int i = blockIdx.x * 256 + threadIdx.x;
    if (i < n) dinv[i] = rsqrtf((float)(counts[i] + 1));  // +1 self loop; deg>0 always
}

// ---------------- 3-pass exclusive scan of counts -> rowptr ----------------
__global__ __launch_bounds__(256) void scan1_kernel(const int* __restrict__ counts,
                                                    int* __restrict__ rowptr,
                                                    int* __restrict__ blocksums, int n) {
    __shared__ int s[256];
    int t = threadIdx.x;
    int i = blockIdx.x * 256 + t;
    int v = (i < n) ? counts[i] : 0;
    s[t] = v;
    __syncthreads();
    for (int off = 1; off < 256; off <<= 1) {
        int add = (t >= off) ? s[t - off] : 0;
        __syncthreads();
        s[t] += add;
        __syncthreads();
    }
    if (i < n) rowptr[i] = s[t] - v;           // exclusive
    if (t == 255) blocksums[blockIdx.x] = s[t];
}

__global__ __launch_bounds__(512) void scan2_kernel(const int* __restrict__ blocksums,
                                                    int* __restrict__ blockoffs,
                                                    int nb, int* __restrict__ rowptr, int n) {
    __shared__ int s[512];
    int t = threadIdx.x;
    int v = (t < nb) ? blocksums[t] : 0;
    s[t] = v;
    __syncthreads();
    for (int off = 1; off < 512; off <<= 1) {
        int add = (t >= off) ? s[t - off] : 0;
        __syncthreads();
        s[t] += add;
        __syncthreads();
    }
    if (t < nb) blockoffs[t] = s[t] - v;       // exclusive
    if (t == 511) rowptr[n] = s[t];            // total = E
}

__global__ __launch_bounds__(256) void scan3_kernel(int* __restrict__ rowptr,
                                                    const int* __restrict__ blockoffs, int n) {
    int i = blockIdx.x * 256 + threadIdx.x;
    if (i < n) rowptr[i] += blockoffs[blockIdx.x];
}

// ---------------- CSR fill ----------------
__global__ __launch_bounds__(256) void csr_fill_kernel(const int* __restrict__ src,
                                                       const int* __restrict__ dst,
                                                       const int* __restrict__ rowptr,
                                                       int* __restrict__ fill,
                                                       int* __restrict__ srcs, int E) {
    int e = blockIdx.x * 256 + threadIdx.x;
    if (e < E) {
        int d = dst[e];
        int pos = rowptr[d] + atomicAdd(&fill[d], 1);
        srcs[pos] = src[e];
    }
}

// ---------------- GEMM1: H1[n,128] = X[n,128] @ W[128,128] ----------------
__global__ __launch_bounds__(256) void gemm1_kernel(const float* __restrict__ X,
                                                    const float* __restrict__ W,
                                                    float* __restrict__ H, int n) {
    __shared__ float Xs[16][IN_DIM];
    int t = threadIdx.x;
    int rowBase = blockIdx.x * 16;
#pragma unroll
    for (int i = 0; i < 8; ++i) {
        int idx = t + i * 256;
        int r = idx >> 7, c = idx & 127;
        int gr = rowBase + r;
        Xs[r][c] = (gr < n) ? X[(size_t)gr * IN_DIM + c] : 0.0f;
    }
    __syncthreads();
    int c = t & 127;
    int rg = t >> 7;  // 0..1
    float acc[8] = {0, 0, 0, 0, 0, 0, 0, 0};
#pragma unroll 4
    for (int k = 0; k < IN_DIM; ++k) {
        float w = W[k * HID_DIM + c];
#pragma unroll
        for (int j = 0; j < 8; ++j) acc[j] += Xs[rg * 8 + j][k] * w;
    }
#pragma unroll
    for (int j = 0; j < 8; ++j) {
        int gr = rowBase + rg * 8 + j;
        if (gr < n) H[(size_t)gr * HID_DIM + c] = acc[j];
    }
}

// ---------------- GEMM2: H2[n,64] = H[n,128] @ W2[128,64] ----------------
__global__ __launch_bounds__(256) void gemm2_kernel(const float* __restrict__ H,
                                                    const float* __restrict__ W,
                                                    float* __restrict__ H2, int n) {
    __shared__ float Hs[16][HID_DIM];
    int t = threadIdx.x;
    int rowBase = blockIdx.x * 16;
#pragma unroll
    for (int i = 0; i < 8; ++i) {
        int idx = t + i * 256;
        int r = idx >> 7, c = idx & 127;
        int gr = rowBase + r;
        Hs[r][c] = (gr < n) ? H[(size_t)gr * HID_DIM + c] : 0.0f;
    }
    __syncthreads();
    int c = t & 63;
    int rg = t >> 6;  // 0..3
    float acc[4] = {0, 0, 0, 0};
#pragma unroll 4
    for (int k = 0; k < HID_DIM; ++k) {
        float w = W[k * OUT_DIM + c];
#pragma unroll
        for (int j = 0; j < 4; ++j) acc[j] += Hs[rg * 4 + j][k] * w;
    }
#pragma unroll
    for (int j = 0; j < 4; ++j) {
        int gr = rowBase + rg * 4 + j;
        if (gr < n) H2[(size_t)gr * OUT_DIM + c] = acc[j];
    }
}

// ---------------- aggregation: one wave per dst node ----------------
// out[v] = act( dinv[v] * sum_{s in N(v)} dinv[s]*Hin[s] + dinv[v]^2*Hin[v] + bias )
template <int DIM, int ACT>  // ACT: 0 = relu, 1 = sigmoid
__global__ __launch_bounds__(256) void agg_kernel(const float* __restrict__ Hin,
                                                  float* __restrict__ Hout,
                                                  const int* __restrict__ rowptr,
                                                  const int* __restrict__ srcs,
                                                  const float* __restrict__ dinv,
                                                  const float* __restrict__ bias, int n) {
    int wave = threadIdx.x >> 6;
    int lane = threadIdx.x & 63;
    int node = blockIdx.x * (256 >> 6) + wave;
    if (node >= n) return;
    float dv = dinv[node];
    float dv2 = dv * dv;
    int start = rowptr[node], end = rowptr[node + 1];
    if (DIM == 128) {
        float ax = 0.0f, ay = 0.0f;
        for (int j = start; j < end; ++j) {
            int s = srcs[j];
            float w = dinv[s];
            float2 v = ((const float2*)(Hin + (size_t)s * 128))[lane];
            ax += w * v.x;
            ay += w * v.y;
        }
        float2 sv = ((const float2*)(Hin + (size_t)node * 128))[lane];
        float ox = ax * dv + dv2 * sv.x + bias[lane * 2 + 0];
        float oy = ay * dv + dv2 * sv.y + bias[lane * 2 + 1];
        if (ACT == 0) {
            ox = fmaxf(ox, 0.0f);
            oy = fmaxf(oy, 0.0f);
        } else {
            ox = 1.0f / (1.0f + expf(-ox));
            oy = 1.0f / (1.0f + expf(-oy));
        }
        float2 o = {ox, oy};
        ((float2*)(Hout + (size_t)node * 128))[lane] = o;
    } else {  // DIM == 64
        float a = 0.0f;
        for (int j = start; j < end; ++j) {
            int s = srcs[j];
            float w = dinv[s];
            a += w * Hin[(size_t)s * 64 + lane];
        }
        float sv = Hin[(size_t)node * 64 + lane];
        float o = a * dv + dv2 * sv + bias[lane];
        if (ACT == 0) o = fmaxf(o, 0.0f);
        else o = 1.0f / (1.0f + expf(-o));
        Hout[(size_t)node * 64 + lane] = o;
    }
}

// ---------------- column mean ----------------
__global__ __launch_bounds__(256) void mean_kernel(const float* __restrict__ Z,
                                                   float* __restrict__ out,
                                                   int total, float inv_n) {
    __shared__ float s[256];
    int t = threadIdx.x;
    float acc = 0.0f;
    for (int i = blockIdx.x * 256 + t; i < total; i += gridDim.x * 256) acc += Z[i];
    s[t] = acc;
    __syncthreads();
    if (t < 64) {
        float v = s[t] + s[t + 64] + s[t + 128] + s[t + 192];
        atomicAdd(&out[t], v * inv_n);
    }
}

// ---------------- launch ----------------
extern "C" void kernel_launch(void* const* d_in, const int* in_sizes, int n_in,
                              void* d_out, int out_size, void* d_ws, size_t ws_size,
                              hipStream_t stream) {
    const float* x  = (const float*)d_in[0];
    const int*   ei = (const int*)d_in[1];
    const float* W1 = (const float*)d_in[2];
    const float* b1 = (const float*)d_in[3];
    const float* W2 = (const float*)d_in[4];
    const float* b2 = (const float*)d_in[5];
    float* out = (float*)d_out;

    const int n = in_sizes[0] / IN_DIM;   // 100000
    const int E = in_sizes[1] / 2;        // 1600000
    const int* srcI = ei;
    const int* dstI = ei + E;

    // workspace carve (256B aligned)
    char* ws = (char*)d_ws;
    size_t off = 0;
    auto carve = [&](size_t bytes) {
        void* p = ws + off;
        off = (off + bytes + 255) & ~(size_t)255;
        return p;
    };
    int*   counts    = (int*)carve((size_t)n * 4);
    int*   fill      = (int*)carve((size_t)n * 4);
    int*   rowptr    = (int*)carve(((size_t)n + 1) * 4);
    int*   blocksums = (int*)carve(512 * 4);
    int*   blockoffs = (int*)carve(512 * 4);
    float* dinv      = (float*)carve((size_t)n * 4);
    int*   srcs      = (int*)carve((size_t)E * 4);
    float* bufA      = (float*)carve((size_t)n * 128 * 4);  // H1, later H2
    float* bufB      = (float*)carve((size_t)n * 128 * 4);  // H (relu), later Z

    const int nbN = (n + 255) / 256;      // 391
    const int nbE = (E + 255) / 256;

    zero_init_kernel<<<nbN, 256, 0, stream>>>(counts, fill, out, n);
    degree_kernel<<<nbE, 256, 0, stream>>>(dstI, counts, E);
    scan1_kernel<<<nbN, 256, 0, stream>>>(counts, rowptr, blocksums, n);
    scan2_kernel<<<1, 512, 0, stream>>>(blocksums, blockoffs, nbN, rowptr, n);
    scan3_kernel<<<nbN, 256, 0, stream>>>(rowptr, blockoffs, n);
    dinv_kernel<<<nbN, 256, 0, stream>>>(counts, dinv, n);
    csr_fill_kernel<<<nbE, 256, 0, stream>>>(srcI, dstI, rowptr, fill, srcs, E);

    gemm1_kernel<<<(n + 15) / 16, 256, 0, stream>>>(x, W1, bufA, n);
    agg_kernel<128, 0><<<(n + 3) / 4, 256, 0, stream>>>(bufA, bufB, rowptr, srcs, dinv, b1, n);
    gemm2_kernel<<<(n + 15) / 16, 256, 0, stream>>>(bufB, W2, bufA, n);
    agg_kernel<64, 1><<<(n + 3) / 4, 256, 0, stream>>>(bufA, bufB, rowptr, srcs, dinv, b2, n);
    mean_kernel<<<1024, 256, 0, stream>>>(bufB, out, n * OUT_DIM, 1.0f / (float)n);
}

// Round 3
// 636.809 us; speedup vs baseline: 1.1327x; 1.1327x over previous
//
#include <hip/hip_runtime.h>
#include <math.h>

#define IN_DIM 128
#define HID_DIM 128
#define OUT_DIM 64

typedef __attribute__((ext_vector_type(8))) short short8;
typedef __attribute__((ext_vector_type(4))) float f32x4;

__device__ __forceinline__ ushort f2bf(float f) {
    uint u = __float_as_uint(f);
    u += 0x7FFF + ((u >> 16) & 1);   // round-to-nearest-even
    return (ushort)(u >> 16);
}
__device__ __forceinline__ float bf2f(ushort h) {
    return __uint_as_float(((uint)h) << 16);
}

// ---------------- init ----------------
__global__ __launch_bounds__(256) void zero_init_kernel(int* __restrict__ counts,
                                                        int* __restrict__ fill,
                                                        float* __restrict__ out, int n) {
    int i = blockIdx.x * 256 + threadIdx.x;
    if (i < n) { counts[i] = 0; fill[i] = 0; }
    if (i < OUT_DIM) out[i] = 0.0f;
}

// ---------------- degree ----------------
__global__ __launch_bounds__(256) void degree_kernel(const int* __restrict__ dst,
                                                     int* __restrict__ counts, int E) {
    int e = blockIdx.x * 256 + threadIdx.x;
    if (e < E) atomicAdd(&counts[dst[e]], 1);
}

__global__ __launch_bounds__(256) void dinv_kernel(const int* __restrict__ counts,
                                                   float* __restrict__ dinv, int n) {
    int i = blockIdx.x * 256 + threadIdx.x;
    if (i < n) dinv[i] = rsqrtf((float)(counts[i] + 1));  // +1 self loop
}

// ---------------- 3-pass exclusive scan of counts -> rowptr ----------------
__global__ __launch_bounds__(256) void scan1_kernel(const int* __restrict__ counts,
                                                    int* __restrict__ rowptr,
                                                    int* __restrict__ blocksums, int n) {
    __shared__ int s[256];
    int t = threadIdx.x;
    int i = blockIdx.x * 256 + t;
    int v = (i < n) ? counts[i] : 0;
    s[t] = v;
    __syncthreads();
    for (int off = 1; off < 256; off <<= 1) {
        int add = (t >= off) ? s[t - off] : 0;
        __syncthreads();
        s[t] += add;
        __syncthreads();
    }
    if (i < n) rowptr[i] = s[t] - v;           // exclusive
    if (t == 255) blocksums[blockIdx.x] = s[t];
}

__global__ __launch_bounds__(512) void scan2_kernel(const int* __restrict__ blocksums,
                                                    int* __restrict__ blockoffs,
                                                    int nb, int* __restrict__ rowptr, int n) {
    __shared__ int s[512];
    int t = threadIdx.x;
    int v = (t < nb) ? blocksums[t] : 0;
    s[t] = v;
    __syncthreads();
    for (int off = 1; off < 512; off <<= 1) {
        int add = (t >= off) ? s[t - off] : 0;
        __syncthreads();
        s[t] += add;
        __syncthreads();
    }
    if (t < nb) blockoffs[t] = s[t] - v;       // exclusive
    if (t == 511) rowptr[n] = s[t];            // total = E
}

__global__ __launch_bounds__(256) void scan3_kernel(int* __restrict__ rowptr,
                                                    const int* __restrict__ blockoffs, int n) {
    int i = blockIdx.x * 256 + threadIdx.x;
    if (i < n) rowptr[i] += blockoffs[blockIdx.x];
}

// ---------------- CSR fill ----------------
__global__ __launch_bounds__(256) void csr_fill_kernel(const int* __restrict__ src,
                                                       const int* __restrict__ dst,
                                                       const int* __restrict__ rowptr,
                                                       int* __restrict__ fill,
                                                       int* __restrict__ srcs, int E) {
    int e = blockIdx.x * 256 + threadIdx.x;
    if (e < E) {
        int d = dst[e];
        int pos = rowptr[d] + atomicAdd(&fill[d], 1);
        srcs[pos] = src[e];
    }
}

// ---------------- fp32 -> bf16 convert (vectorized x4) ----------------
__global__ __launch_bounds__(256) void convx_kernel(const float* __restrict__ X,
                                                    ushort* __restrict__ Xb, int nvec) {
    int i = blockIdx.x * 256 + threadIdx.x;
    if (i < nvec) {
        float4 v = ((const float4*)X)[i];
        ushort4 o;
        o.x = f2bf(v.x); o.y = f2bf(v.y); o.z = f2bf(v.z); o.w = f2bf(v.w);
        ((ushort4*)Xb)[i] = o;
    }
}

// ---------------- pack W[K=128][N] fp32 -> MFMA B-fragment order bf16 ----------------
// Bp[kk][nt][lane][e]; source k = kk*32 + (lane>>4)*8 + e, n = nt*16 + (lane&15)
template <int N>
__global__ __launch_bounds__(256) void packw_kernel(const float* __restrict__ W,
                                                    ushort* __restrict__ Bp) {
    int idx = blockIdx.x * 256 + threadIdx.x;
    if (idx < 128 * N) {
        int e = idx & 7;
        int lane = (idx >> 3) & 63;
        int rest = idx >> 9;
        int nt = rest % (N / 16);
        int kk = rest / (N / 16);
        int k = kk * 32 + (lane >> 4) * 8 + e;
        int n = nt * 16 + (lane & 15);
        Bp[idx] = f2bf(W[k * N + n]);
    }
}

// ---------------- MFMA GEMM: Out[M][N] = bf16( dinv[row] * (A[M][128] @ W) ) ----------------
// one wave per 16-row strip; K=128 in registers; N/16 col tiles
template <int N>
__global__ __launch_bounds__(256) void gemm_kernel(const ushort* __restrict__ A,
                                                   const ushort* __restrict__ Bp,
                                                   const float* __restrict__ dinv,
                                                   ushort* __restrict__ Out, int M) {
    int wid = threadIdx.x >> 6, lane = threadIdx.x & 63;
    int rowBase = (blockIdx.x * 4 + wid) * 16;
    if (rowBase >= M) return;
    int m = lane & 15, kg = lane >> 4;
    const ushort* arow = A + (size_t)(rowBase + m) * 128 + kg * 8;
    short8 af[4];
#pragma unroll
    for (int kk = 0; kk < 4; ++kk)
        af[kk] = *reinterpret_cast<const short8*>(arow + kk * 32);
    float dv[4];
#pragma unroll
    for (int r = 0; r < 4; ++r) dv[r] = dinv[rowBase + kg * 4 + r];
#pragma unroll
    for (int nt = 0; nt < N / 16; ++nt) {
        f32x4 acc = {0.f, 0.f, 0.f, 0.f};
#pragma unroll
        for (int kk = 0; kk < 4; ++kk) {
            short8 bf = *reinterpret_cast<const short8*>(
                Bp + ((size_t)(kk * (N / 16) + nt) * 64 + lane) * 8);
            acc = __builtin_amdgcn_mfma_f32_16x16x32_bf16(af[kk], bf, acc, 0, 0, 0);
        }
        int col = nt * 16 + m;
#pragma unroll
        for (int r = 0; r < 4; ++r) {
            int row = rowBase + kg * 4 + r;
            Out[(size_t)row * N + col] = f2bf(acc[r] * dv[r]);
        }
    }
}

// ---------------- layer-1 aggregation: bf16 rows prescaled by dinv[src] ----------------
// h1[v] = relu( dv * ( sum_{s in N(v)} H1s[s] + H1s[v] ) + b1 ),  128-dim (uint = 2 bf16/lane)
__global__ __launch_bounds__(256) void agg1_kernel(const ushort* __restrict__ Hs,
                                                   ushort* __restrict__ Hout,
                                                   const int* __restrict__ rowptr,
                                                   const int* __restrict__ srcs,
                                                   const float* __restrict__ dinv,
                                                   const float* __restrict__ bias, int n) {
    int wave = threadIdx.x >> 6, lane = threadIdx.x & 63;
    int node = blockIdx.x * 4 + wave;
    if (node >= n) return;
    float dv = dinv[node];
    int start = rowptr[node], end = rowptr[node + 1];
    uint self = ((const uint*)(Hs + (size_t)node * 128))[lane];
    float ax = bf2f((ushort)(self & 0xFFFF));
    float ay = bf2f((ushort)(self >> 16));
    for (int j = start; j < end; ++j) {
        int s = srcs[j];
        uint v = ((const uint*)(Hs + (size_t)s * 128))[lane];
        ax += bf2f((ushort)(v & 0xFFFF));
        ay += bf2f((ushort)(v >> 16));
    }
    float ox = fmaxf(fmaf(ax, dv, bias[2 * lane]), 0.f);
    float oy = fmaxf(fmaf(ay, dv, bias[2 * lane + 1]), 0.f);
    uint o = (uint)f2bf(ox) | ((uint)f2bf(oy) << 16);
    ((uint*)(Hout + (size_t)node * 128))[lane] = o;
}

// ---------------- layer-2 aggregation: 64-dim, sigmoid ----------------
__global__ __launch_bounds__(256) void agg2_kernel(const ushort* __restrict__ Hs,
                                                   ushort* __restrict__ Z,
                                                   const int* __restrict__ rowptr,
                                                   const int* __restrict__ srcs,
                                                   const float* __restrict__ dinv,
                                                   const float* __restrict__ bias, int n) {
    int wave = threadIdx.x >> 6, lane = threadIdx.x & 63;
    int node = blockIdx.x * 4 + wave;
    if (node >= n) return;
    float dv = dinv[node];
    int start = rowptr[node], end = rowptr[node + 1];
    float a = bf2f(Hs[(size_t)node * 64 + lane]);
    for (int j = start; j < end; ++j) {
        int s = srcs[j];
        a += bf2f(Hs[(size_t)s * 64 + lane]);
    }
    float z = fmaf(a, dv, bias[lane]);
    z = 1.0f / (1.0f + __expf(-z));
    Z[(size_t)node * 64 + lane] = f2bf(z);
}

// ---------------- column mean over bf16 Z[n][64] ----------------
__global__ __launch_bounds__(256) void mean_kernel(const ushort* __restrict__ Z,
                                                   float* __restrict__ out,
                                                   int total, float inv_n) {
    __shared__ float s[256];
    int t = threadIdx.x;
    float acc = 0.0f;
    for (int i = blockIdx.x * 256 + t; i < total; i += gridDim.x * 256) acc += bf2f(Z[i]);
    s[t] = acc;
    __syncthreads();
    if (t < 64) {  // col = t & 63 is invariant per thread (256 and grid*256 are multiples of 64)
        atomicAdd(&out[t], (s[t] + s[t + 64] + s[t + 128] + s[t + 192]) * inv_n);
    }
}

// ---------------- launch ----------------
extern "C" void kernel_launch(void* const* d_in, const int* in_sizes, int n_in,
                              void* d_out, int out_size, void* d_ws, size_t ws_size,
                              hipStream_t stream) {
    const float* x  = (const float*)d_in[0];
    const int*   ei = (const int*)d_in[1];
    const float* W1 = (const float*)d_in[2];
    const float* b1 = (const float*)d_in[3];
    const float* W2 = (const float*)d_in[4];
    const float* b2 = (const float*)d_in[5];
    float* out = (float*)d_out;

    const int n = in_sizes[0] / IN_DIM;   // 100000
    const int E = in_sizes[1] / 2;        // 1600000
    const int* srcI = ei;
    const int* dstI = ei + E;

    // workspace carve (256B aligned)
    char* ws = (char*)d_ws;
    size_t off = 0;
    auto carve = [&](size_t bytes) {
        void* p = ws + off;
        off = (off + bytes + 255) & ~(size_t)255;
        return p;
    };
    int*    counts    = (int*)carve((size_t)n * 4);
    int*    fill      = (int*)carve((size_t)n * 4);
    int*    rowptr    = (int*)carve(((size_t)n + 1) * 4);
    int*    blocksums = (int*)carve(512 * 4);
    int*    blockoffs = (int*)carve(512 * 4);
    float*  dinv      = (float*)carve((size_t)n * 4);
    int*    srcs      = (int*)carve((size_t)E * 4);
    ushort* Xb        = (ushort*)carve((size_t)n * 128 * 2);  // X bf16; later reused for H2s/Z
    ushort* W1p       = (ushort*)carve(128 * 128 * 2);
    ushort* W2p       = (ushort*)carve(128 * 64 * 2);
    ushort* H1s       = (ushort*)carve((size_t)n * 128 * 2);  // dinv-prescaled X@W1, bf16
    ushort* h1        = (ushort*)carve((size_t)n * 128 * 2);  // relu output, bf16
    ushort* H2s       = Xb;                                    // alias (Xb dead after gemm1)
    ushort* Zb        = Xb + (size_t)n * 64;                   // alias

    const int nbN = (n + 255) / 256;      // 391
    const int nbE = (E + 255) / 256;

    zero_init_kernel<<<nbN, 256, 0, stream>>>(counts, fill, out, n);
    degree_kernel<<<nbE, 256, 0, stream>>>(dstI, counts, E);
    scan1_kernel<<<nbN, 256, 0, stream>>>(counts, rowptr, blocksums, n);
    scan2_kernel<<<1, 512, 0, stream>>>(blocksums, blockoffs, nbN, rowptr, n);
    scan3_kernel<<<nbN, 256, 0, stream>>>(rowptr, blockoffs, n);
    dinv_kernel<<<nbN, 256, 0, stream>>>(counts, dinv, n);
    csr_fill_kernel<<<nbE, 256, 0, stream>>>(srcI, dstI, rowptr, fill, srcs, E);

    convx_kernel<<<(n * 128 / 4 + 255) / 256, 256, 0, stream>>>(x, Xb, n * 128 / 4);
    packw_kernel<128><<<(128 * 128 + 255) / 256, 256, 0, stream>>>(W1, W1p);
    packw_kernel<64><<<(128 * 64 + 255) / 256, 256, 0, stream>>>(W2, W2p);

    gemm_kernel<128><<<(n / 16 + 3) / 4, 256, 0, stream>>>(Xb, W1p, dinv, H1s, n);
    agg1_kernel<<<(n + 3) / 4, 256, 0, stream>>>(H1s, h1, rowptr, srcs, dinv, b1, n);
    gemm_kernel<64><<<(n / 16 + 3) / 4, 256, 0, stream>>>(h1, W2p, dinv, H2s, n);
    agg2_kernel<<<(n + 3) / 4, 256, 0, stream>>>(H2s, Zb, rowptr, srcs, dinv, b2, n);
    mean_kernel<<<1024, 256, 0, stream>>>(Zb, out, n * OUT_DIM, 1.0f / (float)n);
}

// Round 4
// 421.126 us; speedup vs baseline: 1.7129x; 1.5122x over previous
//
#include <hip/hip_runtime.h>
#include <math.h>

#define IN_DIM 128
#define HID_DIM 128
#define OUT_DIM 64

typedef __attribute__((ext_vector_type(8))) short short8;
typedef __attribute__((ext_vector_type(4))) float f32x4;

__device__ __forceinline__ ushort f2bf(float f) {
    uint u = __float_as_uint(f);
    u += 0x7FFF + ((u >> 16) & 1);   // round-to-nearest-even
    return (ushort)(u >> 16);
}
__device__ __forceinline__ float bf2f(ushort h) {
    return __uint_as_float(((uint)h) << 16);
}
__device__ __forceinline__ float bflo(uint v) { return __uint_as_float(v << 16); }
__device__ __forceinline__ float bfhi(uint v) { return __uint_as_float(v & 0xFFFF0000u); }

// ---------------- init ----------------
__global__ __launch_bounds__(256) void zero_init_kernel(int* __restrict__ counts,
                                                        int* __restrict__ fill,
                                                        float* __restrict__ out, int n) {
    int i = blockIdx.x * 256 + threadIdx.x;
    if (i < n) { counts[i] = 0; fill[i] = 0; }
    if (i < OUT_DIM) out[i] = 0.0f;
}

// ---------------- degree ----------------
__global__ __launch_bounds__(256) void degree_kernel(const int* __restrict__ dst,
                                                     int* __restrict__ counts, int E) {
    int e = blockIdx.x * 256 + threadIdx.x;
    if (e < E) atomicAdd(&counts[dst[e]], 1);
}

__global__ __launch_bounds__(256) void dinv_kernel(const int* __restrict__ counts,
                                                   float* __restrict__ dinv, int n) {
    int i = blockIdx.x * 256 + threadIdx.x;
    if (i < n) dinv[i] = rsqrtf((float)(counts[i] + 1));  // +1 self loop
}

// ---------------- 3-pass exclusive scan of counts -> rowptr ----------------
__global__ __launch_bounds__(256) void scan1_kernel(const int* __restrict__ counts,
                                                    int* __restrict__ rowptr,
                                                    int* __restrict__ blocksums, int n) {
    __shared__ int s[256];
    int t = threadIdx.x;
    int i = blockIdx.x * 256 + t;
    int v = (i < n) ? counts[i] : 0;
    s[t] = v;
    __syncthreads();
    for (int off = 1; off < 256; off <<= 1) {
        int add = (t >= off) ? s[t - off] : 0;
        __syncthreads();
        s[t] += add;
        __syncthreads();
    }
    if (i < n) rowptr[i] = s[t] - v;           // exclusive
    if (t == 255) blocksums[blockIdx.x] = s[t];
}

__global__ __launch_bounds__(512) void scan2_kernel(const int* __restrict__ blocksums,
                                                    int* __restrict__ blockoffs,
                                                    int nb, int* __restrict__ rowptr, int n) {
    __shared__ int s[512];
    int t = threadIdx.x;
    int v = (t < nb) ? blocksums[t] : 0;
    s[t] = v;
    __syncthreads();
    for (int off = 1; off < 512; off <<= 1) {
        int add = (t >= off) ? s[t - off] : 0;
        __syncthreads();
        s[t] += add;
        __syncthreads();
    }
    if (t < nb) blockoffs[t] = s[t] - v;       // exclusive
    if (t == 511) rowptr[n] = s[t];            // total = E
}

__global__ __launch_bounds__(256) void scan3_kernel(int* __restrict__ rowptr,
                                                    const int* __restrict__ blockoffs, int n) {
    int i = blockIdx.x * 256 + threadIdx.x;
    if (i < n) rowptr[i] += blockoffs[blockIdx.x];
}

// ---------------- CSR fill ----------------
__global__ __launch_bounds__(256) void csr_fill_kernel(const int* __restrict__ src,
                                                       const int* __restrict__ dst,
                                                       const int* __restrict__ rowptr,
                                                       int* __restrict__ fill,
                                                       int* __restrict__ srcs, int E) {
    int e = blockIdx.x * 256 + threadIdx.x;
    if (e < E) {
        int d = dst[e];
        int pos = rowptr[d] + atomicAdd(&fill[d], 1);
        srcs[pos] = src[e];
    }
}

// ---------------- fp32 -> bf16 convert (vectorized x4) ----------------
__global__ __launch_bounds__(256) void convx_kernel(const float* __restrict__ X,
                                                    ushort* __restrict__ Xb, int nvec) {
    int i = blockIdx.x * 256 + threadIdx.x;
    if (i < nvec) {
        float4 v = ((const float4*)X)[i];
        ushort4 o;
        o.x = f2bf(v.x); o.y = f2bf(v.y); o.z = f2bf(v.z); o.w = f2bf(v.w);
        ((ushort4*)Xb)[i] = o;
    }
}

// ---------------- pack W[K=128][N] fp32 -> MFMA B-fragment order bf16 ----------------
// Bp[kk][nt][lane][e]; source k = kk*32 + (lane>>4)*8 + e, n = nt*16 + (lane&15)
template <int N>
__global__ __launch_bounds__(256) void packw_kernel(const float* __restrict__ W,
                                                    ushort* __restrict__ Bp) {
    int idx = blockIdx.x * 256 + threadIdx.x;
    if (idx < 128 * N) {
        int e = idx & 7;
        int lane = (idx >> 3) & 63;
        int rest = idx >> 9;
        int nt = rest % (N / 16);
        int kk = rest / (N / 16);
        int k = kk * 32 + (lane >> 4) * 8 + e;
        int n = nt * 16 + (lane & 15);
        Bp[idx] = f2bf(W[k * N + n]);
    }
}

// ---------------- MFMA GEMM: Out[M][N] = bf16( dinv[row] * (A[M][128] @ W) ) ----------------
// one wave per 16-row strip; K=128 in registers; N/16 col tiles
template <int N>
__global__ __launch_bounds__(256) void gemm_kernel(const ushort* __restrict__ A,
                                                   const ushort* __restrict__ Bp,
                                                   const float* __restrict__ dinv,
                                                   ushort* __restrict__ Out, int M) {
    int wid = threadIdx.x >> 6, lane = threadIdx.x & 63;
    int rowBase = (blockIdx.x * 4 + wid) * 16;
    if (rowBase >= M) return;
    int m = lane & 15, kg = lane >> 4;
    const ushort* arow = A + (size_t)(rowBase + m) * 128 + kg * 8;
    short8 af[4];
#pragma unroll
    for (int kk = 0; kk < 4; ++kk)
        af[kk] = *reinterpret_cast<const short8*>(arow + kk * 32);
    float dv[4];
#pragma unroll
    for (int r = 0; r < 4; ++r) dv[r] = dinv[rowBase + kg * 4 + r];
#pragma unroll
    for (int nt = 0; nt < N / 16; ++nt) {
        f32x4 acc = {0.f, 0.f, 0.f, 0.f};
#pragma unroll
        for (int kk = 0; kk < 4; ++kk) {
            short8 bf = *reinterpret_cast<const short8*>(
                Bp + ((size_t)(kk * (N / 16) + nt) * 64 + lane) * 8);
            acc = __builtin_amdgcn_mfma_f32_16x16x32_bf16(af[kk], bf, acc, 0, 0, 0);
        }
        int col = nt * 16 + m;
#pragma unroll
        for (int r = 0; r < 4; ++r) {
            int row = rowBase + kg * 4 + r;
            Out[(size_t)row * N + col] = f2bf(acc[r] * dv[r]);
        }
    }
}

// ---------------- layer-1 aggregation: 128-dim, relu ----------------
// rows prescaled by dinv[src]; masked unroll-8 for MLP; wave id via readfirstlane
// h1[v] = relu( dv * ( sum_{s in N(v)} H1s[s] + H1s[v] ) + b1 )
__global__ __launch_bounds__(256) void agg1_kernel(const ushort* __restrict__ Hs,
                                                   ushort* __restrict__ Hout,
                                                   const int* __restrict__ rowptr,
                                                   const int* __restrict__ srcs,
                                                   const float* __restrict__ dinv,
                                                   const float* __restrict__ bias, int n) {
    int wv = __builtin_amdgcn_readfirstlane(threadIdx.x) >> 6;  // SGPR wave id
    int lane = threadIdx.x & 63;
    int node = blockIdx.x * 4 + wv;
    if (node >= n) return;
    float dv = dinv[node];
    int start = rowptr[node], end = rowptr[node + 1];
    uint self = ((const uint*)(Hs + (size_t)node * 128))[lane];
    float ax = bflo(self), ay = bfhi(self);
    for (int j = start; j < end; j += 8) {
#pragma unroll
        for (int i = 0; i < 8; ++i) {
            int jj = j + i;
            int sj = srcs[min(jj, end - 1)];      // clamped slot = repeat row (L1 hit)
            uint v = ((const uint*)(Hs + (size_t)sj * 128))[lane];
            float w = (jj < end) ? 1.0f : 0.0f;
            ax = fmaf(w, bflo(v), ax);
            ay = fmaf(w, bfhi(v), ay);
        }
    }
    float ox = fmaxf(fmaf(ax, dv, bias[2 * lane]), 0.f);
    float oy = fmaxf(fmaf(ay, dv, bias[2 * lane + 1]), 0.f);
    uint o = (uint)f2bf(ox) | ((uint)f2bf(oy) << 16);
    ((uint*)(Hout + (size_t)node * 128))[lane] = o;
}

// ---------------- layer-2 aggregation: 64-dim, sigmoid ----------------
// 128B rows: two edges per wave (lane halves), uint loads, masked quad per half,
// final half-reduce via shfl_xor(32)
__global__ __launch_bounds__(256) void agg2_kernel(const ushort* __restrict__ Hs,
                                                   ushort* __restrict__ Z,
                                                   const int* __restrict__ rowptr,
                                                   const int* __restrict__ srcs,
                                                   const float* __restrict__ dinv,
                                                   const float* __restrict__ bias, int n) {
    int wv = __builtin_amdgcn_readfirstlane(threadIdx.x) >> 6;
    int lane = threadIdx.x & 63;
    int node = blockIdx.x * 4 + wv;
    if (node >= n) return;
    int half = lane >> 5, c = lane & 31;
    float dv = dinv[node];
    int start = rowptr[node], end = rowptr[node + 1];
    uint self = ((const uint*)(Hs + (size_t)node * 64))[c];
    float ax = half ? 0.f : bflo(self);
    float ay = half ? 0.f : bfhi(self);
    for (int j = start; j < end; j += 8) {
#pragma unroll
        for (int i = 0; i < 4; ++i) {
            int jj = j + 2 * i + half;
            int sj = srcs[min(jj, end - 1)];
            uint v = ((const uint*)(Hs + (size_t)sj * 64))[c];
            float w = (jj < end) ? 1.0f : 0.0f;
            ax = fmaf(w, bflo(v), ax);
            ay = fmaf(w, bfhi(v), ay);
        }
    }
    ax += __shfl_xor(ax, 32);
    ay += __shfl_xor(ay, 32);
    float zx = fmaf(ax, dv, bias[2 * c]);
    float zy = fmaf(ay, dv, bias[2 * c + 1]);
    zx = 1.0f / (1.0f + __expf(-zx));
    zy = 1.0f / (1.0f + __expf(-zy));
    if (half == 0) {
        uint o = (uint)f2bf(zx) | ((uint)f2bf(zy) << 16);
        ((uint*)(Z + (size_t)node * 64))[c] = o;
    }
}

// ---------------- column mean over bf16 Z[n][64] ----------------
__global__ __launch_bounds__(256) void mean_kernel(const ushort* __restrict__ Z,
                                                   float* __restrict__ out,
                                                   int total, float inv_n) {
    __shared__ float s[256];
    int t = threadIdx.x;
    float acc = 0.0f;
    for (int i = blockIdx.x * 256 + t; i < total; i += gridDim.x * 256) acc += bf2f(Z[i]);
    s[t] = acc;
    __syncthreads();
    if (t < 64) {  // col = t & 63 invariant (256 and grid*256 are multiples of 64)
        atomicAdd(&out[t], (s[t] + s[t + 64] + s[t + 128] + s[t + 192]) * inv_n);
    }
}

// ---------------- launch ----------------
extern "C" void kernel_launch(void* const* d_in, const int* in_sizes, int n_in,
                              void* d_out, int out_size, void* d_ws, size_t ws_size,
                              hipStream_t stream) {
    const float* x  = (const float*)d_in[0];
    const int*   ei = (const int*)d_in[1];
    const float* W1 = (const float*)d_in[2];
    const float* b1 = (const float*)d_in[3];
    const float* W2 = (const float*)d_in[4];
    const float* b2 = (const float*)d_in[5];
    float* out = (float*)d_out;

    const int n = in_sizes[0] / IN_DIM;   // 100000
    const int E = in_sizes[1] / 2;        // 1600000
    const int* srcI = ei;
    const int* dstI = ei + E;

    // workspace carve (256B aligned)
    char* ws = (char*)d_ws;
    size_t off = 0;
    auto carve = [&](size_t bytes) {
        void* p = ws + off;
        off = (off + bytes + 255) & ~(size_t)255;
        return p;
    };
    int*    counts    = (int*)carve((size_t)n * 4);
    int*    fill      = (int*)carve((size_t)n * 4);
    int*    rowptr    = (int*)carve(((size_t)n + 1) * 4);
    int*    blocksums = (int*)carve(512 * 4);
    int*    blockoffs = (int*)carve(512 * 4);
    float*  dinv      = (float*)carve((size_t)n * 4);
    int*    srcs      = (int*)carve((size_t)E * 4);
    ushort* Xb        = (ushort*)carve((size_t)n * 128 * 2);  // X bf16; later reused for H2s/Z
    ushort* W1p       = (ushort*)carve(128 * 128 * 2);
    ushort* W2p       = (ushort*)carve(128 * 64 * 2);
    ushort* H1s       = (ushort*)carve((size_t)n * 128 * 2);  // dinv-prescaled X@W1, bf16
    ushort* h1        = (ushort*)carve((size_t)n * 128 * 2);  // relu output, bf16
    ushort* H2s       = Xb;                                    // alias (Xb dead after gemm1)
    ushort* Zb        = Xb + (size_t)n * 64;                   // alias

    const int nbN = (n + 255) / 256;      // 391
    const int nbE = (E + 255) / 256;

    zero_init_kernel<<<nbN, 256, 0, stream>>>(counts, fill, out, n);
    degree_kernel<<<nbE, 256, 0, stream>>>(dstI, counts, E);
    scan1_kernel<<<nbN, 256, 0, stream>>>(counts, rowptr, blocksums, n);
    scan2_kernel<<<1, 512, 0, stream>>>(blocksums, blockoffs, nbN, rowptr, n);
    scan3_kernel<<<nbN, 256, 0, stream>>>(rowptr, blockoffs, n);
    dinv_kernel<<<nbN, 256, 0, stream>>>(counts, dinv, n);
    csr_fill_kernel<<<nbE, 256, 0, stream>>>(srcI, dstI, rowptr, fill, srcs, E);

    convx_kernel<<<(n * 128 / 4 + 255) / 256, 256, 0, stream>>>(x, Xb, n * 128 / 4);
    packw_kernel<128><<<(128 * 128 + 255) / 256, 256, 0, stream>>>(W1, W1p);
    packw_kernel<64><<<(128 * 64 + 255) / 256, 256, 0, stream>>>(W2, W2p);

    gemm_kernel<128><<<(n / 16 + 3) / 4, 256, 0, stream>>>(Xb, W1p, dinv, H1s, n);
    agg1_kernel<<<(n + 3) / 4, 256, 0, stream>>>(H1s, h1, rowptr, srcs, dinv, b1, n);
    gemm_kernel<64><<<(n / 16 + 3) / 4, 256, 0, stream>>>(h1, W2p, dinv, H2s, n);
    agg2_kernel<<<(n + 3) / 4, 256, 0, stream>>>(H2s, Zb, rowptr, srcs, dinv, b2, n);
    mean_kernel<<<1024, 256, 0, stream>>>(Zb, out, n * OUT_DIM, 1.0f / (float)n);
}

// Round 6
// 361.523 us; speedup vs baseline: 1.9953x; 1.1649x over previous
//
#include <hip/hip_runtime.h>
#include <math.h>

#define IN_DIM 128
#define HID_DIM 128
#define OUT_DIM 64

typedef __attribute__((ext_vector_type(8))) short short8;
typedef __attribute__((ext_vector_type(4))) float f32x4;

__device__ __forceinline__ ushort f2bf(float f) {
    uint u = __float_as_uint(f);
    u += 0x7FFF + ((u >> 16) & 1);   // round-to-nearest-even
    return (ushort)(u >> 16);
}
__device__ __forceinline__ float bf2f(ushort h) {
    return __uint_as_float(((uint)h) << 16);
}
__device__ __forceinline__ float bflo(uint v) { return __uint_as_float(v << 16); }
__device__ __forceinline__ float bfhi(uint v) { return __uint_as_float(v & 0xFFFF0000u); }

// ---------------- K1: degree+rank || convx || packw1 || packw2 ----------------
__device__ __forceinline__ void packw_body(const float* __restrict__ W, ushort* __restrict__ Bp,
                                           int idx, int N) {
    // Bp[kk][nt][lane][e]; k = kk*32 + (lane>>4)*8 + e, n = nt*16 + (lane&15)
    int e = idx & 7;
    int lane = (idx >> 3) & 63;
    int rest = idx >> 9;
    int nt = rest % (N / 16);
    int kk = rest / (N / 16);
    int k = kk * 32 + (lane >> 4) * 8 + e;
    int n = nt * 16 + (lane & 15);
    Bp[idx] = f2bf(W[k * N + n]);
}

__global__ __launch_bounds__(256) void k1_kernel(const int* __restrict__ dst,
                                                 int* __restrict__ counts,
                                                 int* __restrict__ rank,
                                                 const float* __restrict__ X,
                                                 ushort* __restrict__ Xb,
                                                 const float* __restrict__ W1,
                                                 ushort* __restrict__ W1p,
                                                 const float* __restrict__ W2,
                                                 ushort* __restrict__ W2p,
                                                 int E, int nvec, int nbDeg, int nbConv) {
    int b = blockIdx.x;
    if (b < nbDeg) {
        int base = (b * 256 + threadIdx.x) * 4;
#pragma unroll
        for (int i = 0; i < 4; ++i) {
            int e = base + i;
            if (e < E) rank[e] = atomicAdd(&counts[dst[e]], 1);
        }
    } else if (b < nbDeg + nbConv) {
        int i = (b - nbDeg) * 256 + threadIdx.x;
        if (i < nvec) {
            float4 v = ((const float4*)X)[i];
            ushort4 o;
            o.x = f2bf(v.x); o.y = f2bf(v.y); o.z = f2bf(v.z); o.w = f2bf(v.w);
            ((ushort4*)Xb)[i] = o;
        }
    } else if (b < nbDeg + nbConv + 64) {
        int idx = (b - nbDeg - nbConv) * 256 + threadIdx.x;   // < 128*128
        packw_body(W1, W1p, idx, 128);
    } else {
        int idx = (b - nbDeg - nbConv - 64) * 256 + threadIdx.x;  // < 128*64
        if (idx < 128 * 64) packw_body(W2, W2p, idx, 64);
    }
}

// ---------------- 3-pass exclusive scan of counts -> rowptr (+dinv in pass 3) -------
__global__ __launch_bounds__(256) void scan1_kernel(const int* __restrict__ counts,
                                                    int* __restrict__ rowptr,
                                                    int* __restrict__ blocksums, int n) {
    __shared__ int s[256];
    int t = threadIdx.x;
    int i = blockIdx.x * 256 + t;
    int v = (i < n) ? counts[i] : 0;
    s[t] = v;
    __syncthreads();
    for (int off = 1; off < 256; off <<= 1) {
        int add = (t >= off) ? s[t - off] : 0;
        __syncthreads();
        s[t] += add;
        __syncthreads();
    }
    if (i < n) rowptr[i] = s[t] - v;           // exclusive
    if (t == 255) blocksums[blockIdx.x] = s[t];
}

__global__ __launch_bounds__(512) void scan2_kernel(const int* __restrict__ blocksums,
                                                    int* __restrict__ blockoffs,
                                                    int nb, int* __restrict__ rowptr, int n) {
    __shared__ int s[512];
    int t = threadIdx.x;
    int v = (t < nb) ? blocksums[t] : 0;
    s[t] = v;
    __syncthreads();
    for (int off = 1; off < 512; off <<= 1) {
        int add = (t >= off) ? s[t - off] : 0;
        __syncthreads();
        s[t] += add;
        __syncthreads();
    }
    if (t < nb) blockoffs[t] = s[t] - v;       // exclusive
    if (t == 511) rowptr[n] = s[t];            // total = E
}

__global__ __launch_bounds__(256) void scan3_kernel(int* __restrict__ rowptr,
                                                    const int* __restrict__ blockoffs,
                                                    const int* __restrict__ counts,
                                                    float* __restrict__ dinv, int n) {
    int i = blockIdx.x * 256 + threadIdx.x;
    if (i < n) {
        rowptr[i] += blockoffs[blockIdx.x];
        dinv[i] = rsqrtf((float)(counts[i] + 1));   // +1 self loop
    }
}

// ---------------- K5: atomic-free CSR fill || MFMA gemm1 ----------------
__global__ __launch_bounds__(256) void k5_kernel(const int* __restrict__ src,
                                                 const int* __restrict__ dst,
                                                 const int* __restrict__ rank,
                                                 const int* __restrict__ rowptr,
                                                 int* __restrict__ srcs,
                                                 const ushort* __restrict__ A,
                                                 const ushort* __restrict__ Bp,
                                                 const float* __restrict__ dinv,
                                                 ushort* __restrict__ Out,
                                                 int E, int M, int nbFill) {
    int b = blockIdx.x;
    if (b < nbFill) {
        int base = (b * 256 + threadIdx.x) * 4;
#pragma unroll
        for (int i = 0; i < 4; ++i) {             // 4 independent scatter chains
            int e = base + i;
            if (e < E) {
                int d = dst[e];
                srcs[rowptr[d] + rank[e]] = src[e];
            }
        }
        return;
    }
    // ---- gemm1: Out[M][128] = bf16( dinv[row] * (A[M][128] @ W1) ) ----
    int wid = threadIdx.x >> 6, lane = threadIdx.x & 63;
    int rowBase = ((b - nbFill) * 4 + wid) * 16;
    if (rowBase >= M) return;
    int m = lane & 15, kg = lane >> 4;
    const ushort* arow = A + (size_t)(rowBase + m) * 128 + kg * 8;
    short8 af[4];
#pragma unroll
    for (int kk = 0; kk < 4; ++kk)
        af[kk] = *reinterpret_cast<const short8*>(arow + kk * 32);
    float dv[4];
#pragma unroll
    for (int r = 0; r < 4; ++r) dv[r] = dinv[rowBase + kg * 4 + r];
#pragma unroll
    for (int nt = 0; nt < 8; ++nt) {
        f32x4 acc = {0.f, 0.f, 0.f, 0.f};
#pragma unroll
        for (int kk = 0; kk < 4; ++kk) {
            short8 bf = *reinterpret_cast<const short8*>(
                Bp + ((size_t)(kk * 8 + nt) * 64 + lane) * 8);
            acc = __builtin_amdgcn_mfma_f32_16x16x32_bf16(af[kk], bf, acc, 0, 0, 0);
        }
        int col = nt * 16 + m;
#pragma unroll
        for (int r = 0; r < 4; ++r) {
            int row = rowBase + kg * 4 + r;
            Out[(size_t)row * 128 + col] = f2bf(acc[r] * dv[r]);
        }
    }
}

// ---------------- MFMA GEMM (layer 2, N=64) ----------------
template <int N>
__global__ __launch_bounds__(256) void gemm_kernel(const ushort* __restrict__ A,
                                                   const ushort* __restrict__ Bp,
                                                   const float* __restrict__ dinv,
                                                   ushort* __restrict__ Out, int M) {
    int wid = threadIdx.x >> 6, lane = threadIdx.x & 63;
    int rowBase = (blockIdx.x * 4 + wid) * 16;
    if (rowBase >= M) return;
    int m = lane & 15, kg = lane >> 4;
    const ushort* arow = A + (size_t)(rowBase + m) * 128 + kg * 8;
    short8 af[4];
#pragma unroll
    for (int kk = 0; kk < 4; ++kk)
        af[kk] = *reinterpret_cast<const short8*>(arow + kk * 32);
    float dv[4];
#pragma unroll
    for (int r = 0; r < 4; ++r) dv[r] = dinv[rowBase + kg * 4 + r];
#pragma unroll
    for (int nt = 0; nt < N / 16; ++nt) {
        f32x4 acc = {0.f, 0.f, 0.f, 0.f};
#pragma unroll
        for (int kk = 0; kk < 4; ++kk) {
            short8 bf = *reinterpret_cast<const short8*>(
                Bp + ((size_t)(kk * (N / 16) + nt) * 64 + lane) * 8);
            acc = __builtin_amdgcn_mfma_f32_16x16x32_bf16(af[kk], bf, acc, 0, 0, 0);
        }
        int col = nt * 16 + m;
#pragma unroll
        for (int r = 0; r < 4; ++r) {
            int row = rowBase + kg * 4 + r;
            Out[(size_t)row * N + col] = f2bf(acc[r] * dv[r]);
        }
    }
}

// ---------------- layer-1 aggregation: 128-dim, relu ----------------
__global__ __launch_bounds__(256) void agg1_kernel(const ushort* __restrict__ Hs,
                                                   ushort* __restrict__ Hout,
                                                   const int* __restrict__ rowptr,
                                                   const int* __restrict__ srcs,
                                                   const float* __restrict__ dinv,
                                                   const float* __restrict__ bias, int n) {
    int wv = __builtin_amdgcn_readfirstlane(threadIdx.x) >> 6;  // SGPR wave id
    int lane = threadIdx.x & 63;
    int node = blockIdx.x * 4 + wv;
    if (node >= n) return;
    float dv = dinv[node];
    int start = rowptr[node], end = rowptr[node + 1];
    uint self = ((const uint*)(Hs + (size_t)node * 128))[lane];
    float ax = bflo(self), ay = bfhi(self);
    for (int j = start; j < end; j += 8) {
#pragma unroll
        for (int i = 0; i < 8; ++i) {
            int jj = j + i;
            int sj = srcs[min(jj, end - 1)];      // clamped slot = repeat row (L1 hit)
            uint v = ((const uint*)(Hs + (size_t)sj * 128))[lane];
            float w = (jj < end) ? 1.0f : 0.0f;
            ax = fmaf(w, bflo(v), ax);
            ay = fmaf(w, bfhi(v), ay);
        }
    }
    float ox = fmaxf(fmaf(ax, dv, bias[2 * lane]), 0.f);
    float oy = fmaxf(fmaf(ay, dv, bias[2 * lane + 1]), 0.f);
    uint o = (uint)f2bf(ox) | ((uint)f2bf(oy) << 16);
    ((uint*)(Hout + (size_t)node * 128))[lane] = o;
}

// ---------------- layer-2 aggregation: 64-dim, sigmoid ----------------
__global__ __launch_bounds__(256) void agg2_kernel(const ushort* __restrict__ Hs,
                                                   ushort* __restrict__ Z,
                                                   const int* __restrict__ rowptr,
                                                   const int* __restrict__ srcs,
                                                   const float* __restrict__ dinv,
                                                   const float* __restrict__ bias, int n) {
    int wv = __builtin_amdgcn_readfirstlane(threadIdx.x) >> 6;
    int lane = threadIdx.x & 63;
    int node = blockIdx.x * 4 + wv;
    if (node >= n) return;
    int half = lane >> 5, c = lane & 31;
    float dv = dinv[node];
    int start = rowptr[node], end = rowptr[node + 1];
    uint self = ((const uint*)(Hs + (size_t)node * 64))[c];
    float ax = half ? 0.f : bflo(self);
    float ay = half ? 0.f : bfhi(self);
    for (int j = start; j < end; j += 8) {
#pragma unroll
        for (int i = 0; i < 4; ++i) {
            int jj = j + 2 * i + half;
            int sj = srcs[min(jj, end - 1)];
            uint v = ((const uint*)(Hs + (size_t)sj * 64))[c];
            float w = (jj < end) ? 1.0f : 0.0f;
            ax = fmaf(w, bflo(v), ax);
            ay = fmaf(w, bfhi(v), ay);
        }
    }
    ax += __shfl_xor(ax, 32);
    ay += __shfl_xor(ay, 32);
    float zx = fmaf(ax, dv, bias[2 * c]);
    float zy = fmaf(ay, dv, bias[2 * c + 1]);
    zx = 1.0f / (1.0f + __expf(-zx));
    zy = 1.0f / (1.0f + __expf(-zy));
    if (half == 0) {
        uint o = (uint)f2bf(zx) | ((uint)f2bf(zy) << 16);
        ((uint*)(Z + (size_t)node * 64))[c] = o;
    }
}

// ---------------- column mean over bf16 Z[n][64] ----------------
__global__ __launch_bounds__(256) void mean_kernel(const ushort* __restrict__ Z,
                                                   float* __restrict__ out,
                                                   int total, float inv_n) {
    __shared__ float s[256];
    int t = threadIdx.x;
    float acc = 0.0f;
    for (int i = blockIdx.x * 256 + t; i < total; i += gridDim.x * 256) acc += bf2f(Z[i]);
    s[t] = acc;
    __syncthreads();
    if (t < 64) {  // col = t & 63 invariant (256 and grid*256 are multiples of 64)
        atomicAdd(&out[t], (s[t] + s[t + 64] + s[t + 128] + s[t + 192]) * inv_n);
    }
}

// ---------------- launch ----------------
extern "C" void kernel_launch(void* const* d_in, const int* in_sizes, int n_in,
                              void* d_out, int out_size, void* d_ws, size_t ws_size,
                              hipStream_t stream) {
    const float* x  = (const float*)d_in[0];
    const int*   ei = (const int*)d_in[1];
    const float* W1 = (const float*)d_in[2];
    const float* b1 = (const float*)d_in[3];
    const float* W2 = (const float*)d_in[4];
    const float* b2 = (const float*)d_in[5];
    float* out = (float*)d_out;

    const int n = in_sizes[0] / IN_DIM;   // 100000
    const int E = in_sizes[1] / 2;        // 1600000
    const int* srcI = ei;
    const int* dstI = ei + E;

    // workspace carve (256B aligned)
    char* ws = (char*)d_ws;
    size_t off = 0;
    auto carve = [&](size_t bytes) {
        void* p = ws + off;
        off = (off + bytes + 255) & ~(size_t)255;
        return p;
    };
    int*    counts    = (int*)carve((size_t)n * 4);
    int*    rank      = (int*)carve((size_t)E * 4);
    int*    rowptr    = (int*)carve(((size_t)n + 1) * 4);
    int*    blocksums = (int*)carve(512 * 4);
    int*    blockoffs = (int*)carve(512 * 4);
    float*  dinv      = (float*)carve((size_t)n * 4);
    int*    srcs      = (int*)carve((size_t)E * 4);
    ushort* Xb        = (ushort*)carve((size_t)n * 128 * 2);  // X bf16; later reused
    ushort* W1p       = (ushort*)carve(128 * 128 * 2);
    ushort* W2p       = (ushort*)carve(128 * 64 * 2);
    ushort* H1s       = (ushort*)carve((size_t)n * 128 * 2);  // dinv-prescaled X@W1
    ushort* h1        = (ushort*)carve((size_t)n * 128 * 2);  // relu output
    ushort* H2s       = Xb;                                    // alias (Xb dead after K5)
    ushort* Zb        = Xb + (size_t)n * 64;                   // alias

    const int nbN    = (n + 255) / 256;            // 391
    const int nbDeg  = (E / 4 + 255) / 256;        // 1563
    const int nvec   = n * 128 / 4;
    const int nbConv = (nvec + 255) / 256;         // 12500
    const int nbPw   = 64 + 32;
    const int nbFill = nbDeg;                      // 4 edges/thread
    const int nbGemm = (n / 16 + 3) / 4;           // 1563

    hipMemsetAsync(counts, 0, (size_t)n * 4, stream);
    hipMemsetAsync(out, 0, OUT_DIM * 4, stream);

    k1_kernel<<<nbDeg + nbConv + nbPw, 256, 0, stream>>>(
        dstI, counts, rank, x, Xb, W1, W1p, W2, W2p, E, nvec, nbDeg, nbConv);
    scan1_kernel<<<nbN, 256, 0, stream>>>(counts, rowptr, blocksums, n);
    scan2_kernel<<<1, 512, 0, stream>>>(blocksums, blockoffs, nbN, rowptr, n);
    scan3_kernel<<<nbN, 256, 0, stream>>>(rowptr, blockoffs, counts, dinv, n);

    k5_kernel<<<nbFill + nbGemm, 256, 0, stream>>>(
        srcI, dstI, rank, rowptr, srcs, Xb, W1p, dinv, H1s, E, n, nbFill);

    agg1_kernel<<<(n + 3) / 4, 256, 0, stream>>>(H1s, h1, rowptr, srcs, dinv, b1, n);
    gemm_kernel<64><<<(n / 16 + 3) / 4, 256, 0, stream>>>(h1, W2p, dinv, H2s, n);
    agg2_kernel<<<(n + 3) / 4, 256, 0, stream>>>(H2s, Zb, rowptr, srcs, dinv, b2, n);
    mean_kernel<<<1024, 256, 0, stream>>>(Zb, out, n * OUT_DIM, 1.0f / (float)n);
}

// Round 7
// 342.664 us; speedup vs baseline: 2.1051x; 1.0550x over previous
//
#include <hip/hip_runtime.h>
#include <math.h>

#define IN_DIM 128
#define OUT_DIM 64
#define BKT 256      // dst-nodes per bucket
#define CHUNK 4096   // edges per binning block
#define NBMAX 512

typedef __attribute__((ext_vector_type(8))) short short8;
typedef __attribute__((ext_vector_type(4))) float f32x4;

__device__ __forceinline__ ushort f2bf(float f) {
    uint u = __float_as_uint(f);
    u += 0x7FFF + ((u >> 16) & 1);   // round-to-nearest-even
    return (ushort)(u >> 16);
}
__device__ __forceinline__ float bf2f(ushort h) {
    return __uint_as_float(((uint)h) << 16);
}
__device__ __forceinline__ float bflo(uint v) { return __uint_as_float(v << 16); }
__device__ __forceinline__ float bfhi(uint v) { return __uint_as_float(v & 0xFFFF0000u); }

// ---------------- pack W[K=128][N] fp32 -> MFMA B-fragment order bf16 ----------------
__device__ __forceinline__ void packw_body(const float* __restrict__ W, ushort* __restrict__ Bp,
                                           int idx, int N) {
    // Bp[kk][nt][lane][e]; k = kk*32 + (lane>>4)*8 + e, n = nt*16 + (lane&15)
    int e = idx & 7;
    int lane = (idx >> 3) & 63;
    int rest = idx >> 9;
    int nt = rest % (N / 16);
    int kk = rest / (N / 16);
    int k = kk * 32 + (lane >> 4) * 8 + e;
    int n = nt * 16 + (lane & 15);
    Bp[idx] = f2bf(W[k * N + n]);
}

// ---------------- B1: bucket histogram (LDS) || packw1 || packw2 ----------------
__global__ __launch_bounds__(256) void b1_kernel(const int* __restrict__ dst,
                                                 int* __restrict__ bucket_counts,
                                                 const float* __restrict__ W1,
                                                 ushort* __restrict__ W1p,
                                                 const float* __restrict__ W2,
                                                 ushort* __restrict__ W2p,
                                                 int E, int nb, int nbBin) {
    __shared__ int lh[NBMAX];
    int b = blockIdx.x, t = threadIdx.x;
    if (b < nbBin) {
        for (int i = t; i < nb; i += 256) lh[i] = 0;
        __syncthreads();
        int base = b * CHUNK;
#pragma unroll
        for (int i = 0; i < CHUNK / 256; ++i) {
            int e = base + i * 256 + t;
            if (e < E) atomicAdd(&lh[((uint)dst[e]) >> 8], 1);
        }
        __syncthreads();
        for (int i = t; i < nb; i += 256) {
            int c = lh[i];
            if (c) atomicAdd(&bucket_counts[i], c);
        }
    } else if (b < nbBin + 64) {
        packw_body(W1, W1p, (b - nbBin) * 256 + t, 128);      // 128*128
    } else {
        packw_body(W2, W2p, (b - nbBin - 64) * 256 + t, 64);  // 128*64
    }
}

// ---------------- B2: exclusive scan of bucket counts (nb <= 511) ----------------
__global__ __launch_bounds__(512) void b2_kernel(const int* __restrict__ bucket_counts,
                                                 int* __restrict__ bucket_off, int nb) {
    __shared__ int s[512];
    int t = threadIdx.x;
    int v = (t < nb) ? bucket_counts[t] : 0;
    s[t] = v;
    __syncthreads();
    for (int off = 1; off < 512; off <<= 1) {
        int add = (t >= off) ? s[t - off] : 0;
        __syncthreads();
        s[t] += add;
        __syncthreads();
    }
    if (t < nb) bucket_off[t] = s[t] - v;
    if (t == 511) bucket_off[nb] = s[511];   // = E
}

// ---------------- B3: bin scatter (edges -> bucket-contiguous pairs) || MFMA gemm1 ----
__global__ __launch_bounds__(256) void b3_kernel(const int* __restrict__ src,
                                                 const int* __restrict__ dst,
                                                 const int* __restrict__ bucket_off,
                                                 int* __restrict__ bucket_fill,
                                                 int2* __restrict__ pairs,
                                                 const float* __restrict__ X,
                                                 const ushort* __restrict__ Bp,
                                                 ushort* __restrict__ H1,
                                                 int E, int M, int nb, int nbBin) {
    __shared__ int lh[NBMAX];
    __shared__ int lf[NBMAX];
    int b = blockIdx.x, t = threadIdx.x;
    if (b < nbBin) {
        for (int i = t; i < nb; i += 256) lh[i] = 0;
        __syncthreads();
        int base = b * CHUNK;
#pragma unroll
        for (int i = 0; i < CHUNK / 256; ++i) {
            int e = base + i * 256 + t;
            if (e < E) atomicAdd(&lh[((uint)dst[e]) >> 8], 1);
        }
        __syncthreads();
        for (int i = t; i < nb; i += 256) {
            int c = lh[i];
            if (c) lf[i] = bucket_off[i] + atomicAdd(&bucket_fill[i], c);
        }
        __syncthreads();
#pragma unroll
        for (int i = 0; i < CHUNK / 256; ++i) {
            int e = base + i * 256 + t;
            if (e < E) {
                int d = dst[e];
                int r = atomicAdd(&lf[((uint)d) >> 8], 1);
                pairs[r] = make_int2(src[e], d);
            }
        }
        return;
    }
    // ---- gemm1: H1[M][128] = bf16( X[M][128] @ W1 )  (unscaled; fp32 X read) ----
    int wid = t >> 6, lane = t & 63;
    int rowBase = ((b - nbBin) * 4 + wid) * 16;
    if (rowBase >= M) return;
    int m = lane & 15, kg = lane >> 4;
    const float* arow = X + (size_t)(rowBase + m) * 128 + kg * 8;
    short8 af[4];
#pragma unroll
    for (int kk = 0; kk < 4; ++kk) {
        float4 a0 = *(const float4*)(arow + kk * 32);
        float4 a1 = *(const float4*)(arow + kk * 32 + 4);
        short8 v;
        v[0] = (short)f2bf(a0.x); v[1] = (short)f2bf(a0.y);
        v[2] = (short)f2bf(a0.z); v[3] = (short)f2bf(a0.w);
        v[4] = (short)f2bf(a1.x); v[5] = (short)f2bf(a1.y);
        v[6] = (short)f2bf(a1.z); v[7] = (short)f2bf(a1.w);
        af[kk] = v;
    }
#pragma unroll
    for (int nt = 0; nt < 8; ++nt) {
        f32x4 acc = {0.f, 0.f, 0.f, 0.f};
#pragma unroll
        for (int kk = 0; kk < 4; ++kk) {
            short8 bf = *reinterpret_cast<const short8*>(Bp + ((size_t)(kk * 8 + nt) * 64 + lane) * 8);
            acc = __builtin_amdgcn_mfma_f32_16x16x32_bf16(af[kk], bf, acc, 0, 0, 0);
        }
        int col = nt * 16 + m;
#pragma unroll
        for (int r = 0; r < 4; ++r) {
            int row = rowBase + kg * 4 + r;
            H1[(size_t)row * 128 + col] = f2bf(acc[r]);
        }
    }
}

// ---------------- B4: per-bucket CSR finalize (rowptr, dinv, srcs) — no global atomics --
__global__ __launch_bounds__(256) void b4_kernel(const int2* __restrict__ pairs,
                                                 const int* __restrict__ bucket_off,
                                                 int* __restrict__ rowptr,
                                                 float* __restrict__ dinv,
                                                 int* __restrict__ srcs,
                                                 int n, int E, int nb) {
    __shared__ int lcnt[BKT];
    __shared__ int ls[BKT];
    __shared__ int lfill[BKT];
    int b = blockIdx.x, t = threadIdx.x;
    int base = b * BKT;
    int bs = min(BKT, n - base);
    int estart = bucket_off[b], eend = bucket_off[b + 1];
    lcnt[t] = 0;
    __syncthreads();
    for (int e = estart + t; e < eend; e += 256)
        atomicAdd(&lcnt[pairs[e].y - base], 1);
    __syncthreads();
    int v = lcnt[t];
    ls[t] = v;
    __syncthreads();
    for (int off = 1; off < 256; off <<= 1) {
        int add = (t >= off) ? ls[t - off] : 0;
        __syncthreads();
        ls[t] += add;
        __syncthreads();
    }
    int excl = ls[t] - v;
    lfill[t] = excl;
    if (t < bs) {
        rowptr[base + t] = estart + excl;
        dinv[base + t] = rsqrtf((float)(v + 1));   // +1 self loop
    }
    if (b == nb - 1 && t == 0) rowptr[n] = E;
    __syncthreads();
    for (int e = estart + t; e < eend; e += 256) {
        int2 p = pairs[e];
        int pos = atomicAdd(&lfill[p.y - base], 1);
        srcs[estart + pos] = p.x;
    }
}

// ---------------- MFMA GEMM (layer 2, N=64, dinv-prescaled output) ----------------
template <int N>
__global__ __launch_bounds__(256) void gemm_kernel(const ushort* __restrict__ A,
                                                   const ushort* __restrict__ Bp,
                                                   const float* __restrict__ dinv,
                                                   ushort* __restrict__ Out, int M) {
    int wid = threadIdx.x >> 6, lane = threadIdx.x & 63;
    int rowBase = (blockIdx.x * 4 + wid) * 16;
    if (rowBase >= M) return;
    int m = lane & 15, kg = lane >> 4;
    const ushort* arow = A + (size_t)(rowBase + m) * 128 + kg * 8;
    short8 af[4];
#pragma unroll
    for (int kk = 0; kk < 4; ++kk)
        af[kk] = *reinterpret_cast<const short8*>(arow + kk * 32);
    float dv[4];
#pragma unroll
    for (int r = 0; r < 4; ++r) dv[r] = dinv[rowBase + kg * 4 + r];
#pragma unroll
    for (int nt = 0; nt < N / 16; ++nt) {
        f32x4 acc = {0.f, 0.f, 0.f, 0.f};
#pragma unroll
        for (int kk = 0; kk < 4; ++kk) {
            short8 bf = *reinterpret_cast<const short8*>(
                Bp + ((size_t)(kk * (N / 16) + nt) * 64 + lane) * 8);
            acc = __builtin_amdgcn_mfma_f32_16x16x32_bf16(af[kk], bf, acc, 0, 0, 0);
        }
        int col = nt * 16 + m;
#pragma unroll
        for (int r = 0; r < 4; ++r) {
            int row = rowBase + kg * 4 + r;
            Out[(size_t)row * N + col] = f2bf(acc[r] * dv[r]);
        }
    }
}

// ---------------- layer-1 aggregation: 128-dim, relu, per-edge dinv[src] ----------------
// h1[v] = relu( dv * ( sum_s dinv[s]*H1[s] + dv*H1[v] ) + b1 )
__global__ __launch_bounds__(256) void agg1_kernel(const ushort* __restrict__ Hs,
                                                   ushort* __restrict__ Hout,
                                                   const int* __restrict__ rowptr,
                                                   const int* __restrict__ srcs,
                                                   const float* __restrict__ dinv,
                                                   const float* __restrict__ bias, int n) {
    int wv = __builtin_amdgcn_readfirstlane(threadIdx.x) >> 6;
    int lane = threadIdx.x & 63;
    int node = blockIdx.x * 4 + wv;
    if (node >= n) return;
    float dv = dinv[node];
    int start = rowptr[node], end = rowptr[node + 1];
    uint self = ((const uint*)(Hs + (size_t)node * 128))[lane];
    float ax = dv * bflo(self), ay = dv * bfhi(self);
    for (int j = start; j < end; j += 8) {
#pragma unroll
        for (int i = 0; i < 8; ++i) {
            int jj = j + i;
            int sj = srcs[min(jj, end - 1)];        // uniform per wave; clamped = L1 hit
            float w = (jj < end) ? dinv[sj] : 0.0f; // dinv is L2/L3-hot (400 KB)
            uint v = ((const uint*)(Hs + (size_t)sj * 128))[lane];
            ax = fmaf(w, bflo(v), ax);
            ay = fmaf(w, bfhi(v), ay);
        }
    }
    float ox = fmaxf(fmaf(ax, dv, bias[2 * lane]), 0.f);
    float oy = fmaxf(fmaf(ay, dv, bias[2 * lane + 1]), 0.f);
    uint o = (uint)f2bf(ox) | ((uint)f2bf(oy) << 16);
    ((uint*)(Hout + (size_t)node * 128))[lane] = o;
}

// ---------------- layer-2 aggregation: 64-dim, sigmoid (prescaled rows) ----------------
__global__ __launch_bounds__(256) void agg2_kernel(const ushort* __restrict__ Hs,
                                                   ushort* __restrict__ Z,
                                                   const int* __restrict__ rowptr,
                                                   const int* __restrict__ srcs,
                                                   const float* __restrict__ dinv,
                                                   const float* __restrict__ bias, int n) {
    int wv = __builtin_amdgcn_readfirstlane(threadIdx.x) >> 6;
    int lane = threadIdx.x & 63;
    int node = blockIdx.x * 4 + wv;
    if (node >= n) return;
    int half = lane >> 5, c = lane & 31;
    float dv = dinv[node];
    int start = rowptr[node], end = rowptr[node + 1];
    uint self = ((const uint*)(Hs + (size_t)node * 64))[c];
    float ax = half ? 0.f : bflo(self);
    float ay = half ? 0.f : bfhi(self);
    for (int j = start; j < end; j += 8) {
#pragma unroll
        for (int i = 0; i < 4; ++i) {
            int jj = j + 2 * i + half;
            int sj = srcs[min(jj, end - 1)];
            uint v = ((const uint*)(Hs + (size_t)sj * 64))[c];
            float w = (jj < end) ? 1.0f : 0.0f;
            ax = fmaf(w, bflo(v), ax);
            ay = fmaf(w, bfhi(v), ay);
        }
    }
    ax += __shfl_xor(ax, 32);
    ay += __shfl_xor(ay, 32);
    float zx = fmaf(ax, dv, bias[2 * c]);
    float zy = fmaf(ay, dv, bias[2 * c + 1]);
    zx = 1.0f / (1.0f + __expf(-zx));
    zy = 1.0f / (1.0f + __expf(-zy));
    if (half == 0) {
        uint o = (uint)f2bf(zx) | ((uint)f2bf(zy) << 16);
        ((uint*)(Z + (size_t)node * 64))[c] = o;
    }
}

// ---------------- column mean over bf16 Z[n][64] ----------------
__global__ __launch_bounds__(256) void mean_kernel(const ushort* __restrict__ Z,
                                                   float* __restrict__ out,
                                                   int total, float inv_n) {
    __shared__ float s[256];
    int t = threadIdx.x;
    float acc = 0.0f;
    for (int i = blockIdx.x * 256 + t; i < total; i += gridDim.x * 256) acc += bf2f(Z[i]);
    s[t] = acc;
    __syncthreads();
    if (t < 64) {
        atomicAdd(&out[t], (s[t] + s[t + 64] + s[t + 128] + s[t + 192]) * inv_n);
    }
}

// ---------------- launch ----------------
extern "C" void kernel_launch(void* const* d_in, const int* in_sizes, int n_in,
                              void* d_out, int out_size, void* d_ws, size_t ws_size,
                              hipStream_t stream) {
    const float* x   = (const float*)d_in[0];
    const int*   ei  = (const int*)d_in[1];
    const float* W1  = (const float*)d_in[2];
    const float* bi1 = (const float*)d_in[3];
    const float* W2  = (const float*)d_in[4];
    const float* bi2 = (const float*)d_in[5];
    float* out = (float*)d_out;

    const int n = in_sizes[0] / IN_DIM;   // 100000
    const int E = in_sizes[1] / 2;        // 1600000
    const int* srcI = ei;
    const int* dstI = ei + E;

    // workspace carve (256B aligned)
    char* ws = (char*)d_ws;
    size_t off = 0;
    auto carve = [&](size_t bytes) {
        void* p = ws + off;
        off = (off + bytes + 255) & ~(size_t)255;
        return p;
    };
    int*    bucket_counts = (int*)carve(NBMAX * 4);
    int*    bucket_fill   = (int*)carve(NBMAX * 4);
    int*    bucket_off    = (int*)carve((NBMAX + 1) * 4);
    int*    rowptr        = (int*)carve(((size_t)n + 1) * 4);
    float*  dinv          = (float*)carve((size_t)n * 4);
    int*    srcs          = (int*)carve((size_t)E * 4);
    int2*   pairs         = (int2*)carve((size_t)E * 8);
    ushort* W1p           = (ushort*)carve(128 * 128 * 2);
    ushort* W2p           = (ushort*)carve(128 * 64 * 2);
    ushort* H1            = (ushort*)carve((size_t)n * 128 * 2);  // unscaled X@W1
    ushort* h1            = (ushort*)carve((size_t)n * 128 * 2);  // relu output
    ushort* H2s           = (ushort*)carve((size_t)n * 64 * 2);   // dinv-prescaled h1@W2
    ushort* Zb            = (ushort*)carve((size_t)n * 64 * 2);   // sigmoid output

    const int nb     = (n + BKT - 1) / BKT;        // 391 buckets
    const int nbBin  = (E + CHUNK - 1) / CHUNK;    // 391 binning blocks
    const int nbGemm = (n / 16 + 3) / 4;           // 1563

    hipMemsetAsync(bucket_counts, 0, NBMAX * 4, stream);
    hipMemsetAsync(bucket_fill, 0, NBMAX * 4, stream);
    hipMemsetAsync(out, 0, OUT_DIM * 4, stream);

    b1_kernel<<<nbBin + 96, 256, 0, stream>>>(dstI, bucket_counts, W1, W1p, W2, W2p,
                                              E, nb, nbBin);
    b2_kernel<<<1, 512, 0, stream>>>(bucket_counts, bucket_off, nb);
    b3_kernel<<<nbBin + nbGemm, 256, 0, stream>>>(srcI, dstI, bucket_off, bucket_fill,
                                                  pairs, x, W1p, H1, E, n, nb, nbBin);
    b4_kernel<<<nb, 256, 0, stream>>>(pairs, bucket_off, rowptr, dinv, srcs, n, E, nb);

    agg1_kernel<<<(n + 3) / 4, 256, 0, stream>>>(H1, h1, rowptr, srcs, dinv, bi1, n);
    gemm_kernel<64><<<nbGemm, 256, 0, stream>>>(h1, W2p, dinv, H2s, n);
    agg2_kernel<<<(n + 3) / 4, 256, 0, stream>>>(H2s, Zb, rowptr, srcs, dinv, bi2, n);
    mean_kernel<<<1024, 256, 0, stream>>>(Zb, out, n * OUT_DIM, 1.0f / (float)n);
}

// Round 9
// 327.208 us; speedup vs baseline: 2.2045x; 1.0472x over previous
//
#include <hip/hip_runtime.h>
#include <math.h>

#define IN_DIM 128
#define OUT_DIM 64
#define BKT 256      // dst-nodes per bucket
#define CHUNK 4096   // edges per binning block
#define NBMAX 512

typedef __attribute__((ext_vector_type(8))) short short8;
typedef __attribute__((ext_vector_type(4))) float f32x4;
typedef __attribute__((ext_vector_type(2))) float f32x2;

__device__ __forceinline__ ushort f2bf(float f) {
    uint u = __float_as_uint(f);
    u += 0x7FFF + ((u >> 16) & 1);   // round-to-nearest-even
    return (ushort)(u >> 16);
}
__device__ __forceinline__ float bf2f(ushort h) {
    return __uint_as_float(((uint)h) << 16);
}
__device__ __forceinline__ float bflo(uint v) { return __uint_as_float(v << 16); }
__device__ __forceinline__ float bfhi(uint v) { return __uint_as_float(v & 0xFFFF0000u); }

__device__ __forceinline__ uchar f2fp8(float v) {
    return (uchar)(__builtin_amdgcn_cvt_pk_fp8_f32(v, v, 0, false) & 0xFF);
}

// ---------------- pack W[K=128][N] fp32 -> MFMA B-fragment order bf16 ----------------
__device__ __forceinline__ void packw_body(const float* __restrict__ W, ushort* __restrict__ Bp,
                                           int idx, int N) {
    int e = idx & 7;
    int lane = (idx >> 3) & 63;
    int rest = idx >> 9;
    int nt = rest % (N / 16);
    int kk = rest / (N / 16);
    int k = kk * 32 + (lane >> 4) * 8 + e;
    int n = nt * 16 + (lane & 15);
    Bp[idx] = f2bf(W[k * N + n]);
}

// ---------------- B1: bucket histogram (LDS) || packw1 || packw2 ----------------
__global__ __launch_bounds__(256) void b1_kernel(const int* __restrict__ dst,
                                                 int* __restrict__ bucket_counts,
                                                 const float* __restrict__ W1,
                                                 ushort* __restrict__ W1p,
                                                 const float* __restrict__ W2,
                                                 ushort* __restrict__ W2p,
                                                 int E, int nb, int nbBin) {
    __shared__ int lh[NBMAX];
    int b = blockIdx.x, t = threadIdx.x;
    if (b < nbBin) {
        for (int i = t; i < nb; i += 256) lh[i] = 0;
        __syncthreads();
        int base = b * CHUNK;
#pragma unroll
        for (int i = 0; i < CHUNK / 256; ++i) {
            int e = base + i * 256 + t;
            if (e < E) atomicAdd(&lh[((uint)dst[e]) >> 8], 1);
        }
        __syncthreads();
        for (int i = t; i < nb; i += 256) {
            int c = lh[i];
            if (c) atomicAdd(&bucket_counts[i], c);
        }
    } else if (b < nbBin + 64) {
        packw_body(W1, W1p, (b - nbBin) * 256 + t, 128);      // 128*128
    } else {
        packw_body(W2, W2p, (b - nbBin - 64) * 256 + t, 64);  // 128*64
    }
}

// ---------------- B2: exclusive scan of bucket counts (nb <= 511) ----------------
__global__ __launch_bounds__(512) void b2_kernel(const int* __restrict__ bucket_counts,
                                                 int* __restrict__ bucket_off, int nb) {
    __shared__ int s[512];
    int t = threadIdx.x;
    int v = (t < nb) ? bucket_counts[t] : 0;
    s[t] = v;
    __syncthreads();
    for (int off = 1; off < 512; off <<= 1) {
        int add = (t >= off) ? s[t - off] : 0;
        __syncthreads();
        s[t] += add;
        __syncthreads();
    }
    if (t < nb) bucket_off[t] = s[t] - v;
    if (t == 511) bucket_off[nb] = s[511];   // = E
}

// ---------------- B3: bin scatter (packed pairs) || MFMA gemm1 -> fp8 H1 ----------
__global__ __launch_bounds__(256) void b3_kernel(const int* __restrict__ src,
                                                 const int* __restrict__ dst,
                                                 const int* __restrict__ bucket_off,
                                                 int* __restrict__ bucket_fill,
                                                 uint* __restrict__ pairs,
                                                 const float* __restrict__ X,
                                                 const ushort* __restrict__ Bp,
                                                 uchar* __restrict__ H1,
                                                 int E, int M, int nb, int nbBin) {
    __shared__ int lh[NBMAX];
    __shared__ int lf[NBMAX];
    int b = blockIdx.x, t = threadIdx.x;
    if (b < nbBin) {
        for (int i = t; i < nb; i += 256) lh[i] = 0;
        __syncthreads();
        int base = b * CHUNK;
#pragma unroll
        for (int i = 0; i < CHUNK / 256; ++i) {
            int e = base + i * 256 + t;
            if (e < E) atomicAdd(&lh[((uint)dst[e]) >> 8], 1);
        }
        __syncthreads();
        for (int i = t; i < nb; i += 256) {
            int c = lh[i];
            if (c) lf[i] = bucket_off[i] + atomicAdd(&bucket_fill[i], c);
        }
        __syncthreads();
#pragma unroll
        for (int i = 0; i < CHUNK / 256; ++i) {
            int e = base + i * 256 + t;
            if (e < E) {
                int d = dst[e];
                int r = atomicAdd(&lf[((uint)d) >> 8], 1);
                pairs[r] = (((uint)src[e]) << 8) | ((uint)d & 255);  // src < 2^17
            }
        }
        return;
    }
    // ---- gemm1: H1[M][128] = fp8( X[M][128] @ W1 )  (unscaled) ----
    int wid = t >> 6, lane = t & 63;
    int rowBase = ((b - nbBin) * 4 + wid) * 16;
    if (rowBase >= M) return;
    int m = lane & 15, kg = lane >> 4;
    const float* arow = X + (size_t)(rowBase + m) * 128 + kg * 8;
    short8 af[4];
#pragma unroll
    for (int kk = 0; kk < 4; ++kk) {
        float4 a0 = *(const float4*)(arow + kk * 32);
        float4 a1 = *(const float4*)(arow + kk * 32 + 4);
        short8 v;
        v[0] = (short)f2bf(a0.x); v[1] = (short)f2bf(a0.y);
        v[2] = (short)f2bf(a0.z); v[3] = (short)f2bf(a0.w);
        v[4] = (short)f2bf(a1.x); v[5] = (short)f2bf(a1.y);
        v[6] = (short)f2bf(a1.z); v[7] = (short)f2bf(a1.w);
        af[kk] = v;
    }
#pragma unroll
    for (int nt = 0; nt < 8; ++nt) {
        f32x4 acc = {0.f, 0.f, 0.f, 0.f};
#pragma unroll
        for (int kk = 0; kk < 4; ++kk) {
            short8 bf = *reinterpret_cast<const short8*>(Bp + ((size_t)(kk * 8 + nt) * 64 + lane) * 8);
            acc = __builtin_amdgcn_mfma_f32_16x16x32_bf16(af[kk], bf, acc, 0, 0, 0);
        }
        int col = nt * 16 + m;
#pragma unroll
        for (int r = 0; r < 4; ++r) {
            int row = rowBase + kg * 4 + r;
            H1[(size_t)row * 128 + col] = f2fp8(acc[r]);
        }
    }
}

// ---------------- B4: per-bucket CSR finalize (rowptr, dinv, srcs) ----------------
__global__ __launch_bounds__(256) void b4_kernel(const uint* __restrict__ pairs,
                                                 const int* __restrict__ bucket_off,
                                                 int* __restrict__ rowptr,
                                                 float* __restrict__ dinv,
                                                 int* __restrict__ srcs,
                                                 int n, int E, int nb) {
    __shared__ int lcnt[BKT];
    __shared__ int ls[BKT];
    __shared__ int lfill[BKT];
    int b = blockIdx.x, t = threadIdx.x;
    int base = b * BKT;
    int bs = min(BKT, n - base);
    int estart = bucket_off[b], eend = bucket_off[b + 1];
    lcnt[t] = 0;
    __syncthreads();
    for (int e = estart + t; e < eend; e += 256)
        atomicAdd(&lcnt[pairs[e] & 255], 1);
    __syncthreads();
    int v = lcnt[t];
    ls[t] = v;
    __syncthreads();
    for (int off = 1; off < 256; off <<= 1) {
        int add = (t >= off) ? ls[t - off] : 0;
        __syncthreads();
        ls[t] += add;
        __syncthreads();
    }
    int excl = ls[t] - v;
    lfill[t] = excl;
    if (t < bs) {
        rowptr[base + t] = estart + excl;
        dinv[base + t] = rsqrtf((float)(v + 1));   // +1 self loop
    }
    if (b == nb - 1 && t == 0) rowptr[n] = E;
    __syncthreads();
    for (int e = estart + t; e < eend; e += 256) {
        uint p = pairs[e];
        int pos = atomicAdd(&lfill[p & 255], 1);
        srcs[estart + pos] = (int)(p >> 8);
    }
}

// ---------------- gemm2: H2[M][64] = fp8( dinv[row] * (h1[M][128] @ W2) ) ------------
__global__ __launch_bounds__(256) void gemm2_kernel(const ushort* __restrict__ A,
                                                    const ushort* __restrict__ Bp,
                                                    const float* __restrict__ dinv,
                                                    uchar* __restrict__ Out, int M) {
    int wid = threadIdx.x >> 6, lane = threadIdx.x & 63;
    int rowBase = (blockIdx.x * 4 + wid) * 16;
    if (rowBase >= M) return;
    int m = lane & 15, kg = lane >> 4;
    const ushort* arow = A + (size_t)(rowBase + m) * 128 + kg * 8;
    short8 af[4];
#pragma unroll
    for (int kk = 0; kk < 4; ++kk)
        af[kk] = *reinterpret_cast<const short8*>(arow + kk * 32);
    float dv[4];
#pragma unroll
    for (int r = 0; r < 4; ++r) dv[r] = dinv[rowBase + kg * 4 + r];
#pragma unroll
    for (int nt = 0; nt < 4; ++nt) {
        f32x4 acc = {0.f, 0.f, 0.f, 0.f};
#pragma unroll
        for (int kk = 0; kk < 4; ++kk) {
            short8 bf = *reinterpret_cast<const short8*>(
                Bp + ((size_t)(kk * 4 + nt) * 64 + lane) * 8);
            acc = __builtin_amdgcn_mfma_f32_16x16x32_bf16(af[kk], bf, acc, 0, 0, 0);
        }
        int col = nt * 16 + m;
#pragma unroll
        for (int r = 0; r < 4; ++r) {
            int row = rowBase + kg * 4 + r;
            Out[(size_t)row * 64 + col] = f2fp8(acc[r] * dv[r]);
        }
    }
}

// ---------------- layer-1 aggregation: fp8 gather, 128-dim, relu -------------------
// h1[v] = relu( dv * ( dv*H1[v] + sum_s dinv[s]*H1[s] ) + b1 )
__global__ __launch_bounds__(256) void agg1_kernel(const uchar* __restrict__ Hs,
                                                   ushort* __restrict__ Hout,
                                                   const int* __restrict__ rowptr,
                                                   const int* __restrict__ srcs,
                                                   const float* __restrict__ dinv,
                                                   const float* __restrict__ bias, int n) {
    int wv = __builtin_amdgcn_readfirstlane(threadIdx.x) >> 6;
    int lane = threadIdx.x & 63;
    int node = blockIdx.x * 4 + wv;
    if (node >= n) return;
    float dv = dinv[node];
    int start = rowptr[node], end = rowptr[node + 1];
    ushort self = ((const ushort*)(Hs + (size_t)node * 128))[lane];
    f32x2 sv = __builtin_amdgcn_cvt_pk_f32_fp8((int)self, false);
    float ax = dv * sv[0], ay = dv * sv[1];
    for (int j = start; j < end; j += 16) {
#pragma unroll
        for (int i = 0; i < 16; ++i) {
            int jj = j + i;
            int sj = srcs[min(jj, end - 1)];          // uniform; clamped slot = L1 hit
            float w = (jj < end) ? dinv[sj] : 0.0f;   // dinv L2-hot (400 KB)
            ushort u = ((const ushort*)(Hs + (size_t)sj * 128))[lane];
            f32x2 p = __builtin_amdgcn_cvt_pk_f32_fp8((int)u, false);
            ax = fmaf(w, p[0], ax);
            ay = fmaf(w, p[1], ay);
        }
    }
    float ox = fmaxf(fmaf(ax, dv, bias[2 * lane]), 0.f);
    float oy = fmaxf(fmaf(ay, dv, bias[2 * lane + 1]), 0.f);
    uint o = (uint)f2bf(ox) | ((uint)f2bf(oy) << 16);
    ((uint*)(Hout + (size_t)node * 128))[lane] = o;
}

// ---------------- layer-2 aggregation: fp8 gather, 64-dim, sigmoid -----------------
// quarter-wave per edge: 16 lanes x uint = 64B row; 4 edges x unroll-4 = 16 rows in flight
__global__ __launch_bounds__(256) void agg2_kernel(const uchar* __restrict__ Hs,
                                                   ushort* __restrict__ Z,
                                                   const int* __restrict__ rowptr,
                                                   const int* __restrict__ srcs,
                                                   const float* __restrict__ dinv,
                                                   const float* __restrict__ bias, int n) {
    int wv = __builtin_amdgcn_readfirstlane(threadIdx.x) >> 6;
    int lane = threadIdx.x & 63;
    int node = blockIdx.x * 4 + wv;
    if (node >= n) return;
    int q = lane >> 4, c = lane & 15;
    float dv = dinv[node];
    int start = rowptr[node], end = rowptr[node + 1];
    float a0 = 0.f, a1 = 0.f, a2 = 0.f, a3 = 0.f;
    if (q == 0) {
        uint s = ((const uint*)(Hs + (size_t)node * 64))[c];
        f32x2 lo = __builtin_amdgcn_cvt_pk_f32_fp8((int)s, false);
        f32x2 hi = __builtin_amdgcn_cvt_pk_f32_fp8((int)s, true);
        a0 = lo[0]; a1 = lo[1]; a2 = hi[0]; a3 = hi[1];
    }
    for (int j = start; j < end; j += 16) {
#pragma unroll
        for (int i = 0; i < 4; ++i) {
            int jj = j + 4 * i + q;
            int sj = srcs[min(jj, end - 1)];
            float w = (jj < end) ? 1.0f : 0.0f;
            uint v = ((const uint*)(Hs + (size_t)sj * 64))[c];
            f32x2 lo = __builtin_amdgcn_cvt_pk_f32_fp8((int)v, false);
            f32x2 hi = __builtin_amdgcn_cvt_pk_f32_fp8((int)v, true);
            a0 = fmaf(w, lo[0], a0);
            a1 = fmaf(w, lo[1], a1);
            a2 = fmaf(w, hi[0], a2);
            a3 = fmaf(w, hi[1], a3);
        }
    }
#pragma unroll
    for (int d = 16; d <= 32; d <<= 1) {
        a0 += __shfl_xor(a0, d);
        a1 += __shfl_xor(a1, d);
        a2 += __shfl_xor(a2, d);
        a3 += __shfl_xor(a3, d);
    }
    if (q == 0) {
        float4 bv = *(const float4*)(bias + 4 * c);
        float z0 = 1.0f / (1.0f + __expf(-fmaf(a0, dv, bv.x)));
        float z1 = 1.0f / (1.0f + __expf(-fmaf(a1, dv, bv.y)));
        float z2 = 1.0f / (1.0f + __expf(-fmaf(a2, dv, bv.z)));
        float z3 = 1.0f / (1.0f + __expf(-fmaf(a3, dv, bv.w)));
        uint2 o;
        o.x = (uint)f2bf(z0) | ((uint)f2bf(z1) << 16);
        o.y = (uint)f2bf(z2) | ((uint)f2bf(z3) << 16);
        ((uint2*)(Z + (size_t)node * 64))[c] = o;
    }
}

// ---------------- column mean over bf16 Z[n][64] ----------------
__global__ __launch_bounds__(256) void mean_kernel(const ushort* __restrict__ Z,
                                                   float* __restrict__ out,
                                                   int total, float inv_n) {
    __shared__ float s[256];
    int t = threadIdx.x;
    float acc = 0.0f;
    for (int i = blockIdx.x * 256 + t; i < total; i += gridDim.x * 256) acc += bf2f(Z[i]);
    s[t] = acc;
    __syncthreads();
    if (t < 64) {
        atomicAdd(&out[t], (s[t] + s[t + 64] + s[t + 128] + s[t + 192]) * inv_n);
    }
}

// ---------------- launch ----------------
extern "C" void kernel_launch(void* const* d_in, const int* in_sizes, int n_in,
                              void* d_out, int out_size, void* d_ws, size_t ws_size,
                              hipStream_t stream) {
    const float* x   = (const float*)d_in[0];
    const int*   ei  = (const int*)d_in[1];
    const float* W1  = (const float*)d_in[2];
    const float* bi1 = (const float*)d_in[3];
    const float* W2  = (const float*)d_in[4];
    const float* bi2 = (const float*)d_in[5];
    float* out = (float*)d_out;

    const int n = in_sizes[0] / IN_DIM;   // 100000
    const int E = in_sizes[1] / 2;        // 1600000
    const int* srcI = ei;
    const int* dstI = ei + E;

    // workspace carve (256B aligned)
    char* ws = (char*)d_ws;
    size_t off = 0;
    auto carve = [&](size_t bytes) {
        void* p = ws + off;
        off = (off + bytes + 255) & ~(size_t)255;
        return p;
    };
    int*    bucket_counts = (int*)carve(NBMAX * 4);
    int*    bucket_fill   = (int*)carve(NBMAX * 4);
    int*    bucket_off    = (int*)carve((NBMAX + 1) * 4);
    int*    rowptr        = (int*)carve(((size_t)n + 1) * 4);
    float*  dinv          = (float*)carve((size_t)n * 4);
    int*    srcs          = (int*)carve((size_t)E * 4);
    uint*   pairs         = (uint*)carve((size_t)E * 4);
    ushort* W1p           = (ushort*)carve(128 * 128 * 2);
    ushort* W2p           = (ushort*)carve(128 * 64 * 2);
    uchar*  H1            = (uchar*)carve((size_t)n * 128);      // fp8, unscaled X@W1
    ushort* h1            = (ushort*)carve((size_t)n * 128 * 2); // bf16 relu output
    uchar*  H2s           = (uchar*)carve((size_t)n * 64);       // fp8, prescaled h1@W2
    ushort* Zb            = (ushort*)carve((size_t)n * 64 * 2);  // bf16 sigmoid output

    const int nb     = (n + BKT - 1) / BKT;        // 391 buckets
    const int nbBin  = (E + CHUNK - 1) / CHUNK;    // 391 binning blocks
    const int nbGemm = (n / 16 + 3) / 4;           // 1563

    hipMemsetAsync(bucket_counts, 0, NBMAX * 4, stream);
    hipMemsetAsync(bucket_fill, 0, NBMAX * 4, stream);
    hipMemsetAsync(out, 0, OUT_DIM * 4, stream);

    b1_kernel<<<nbBin + 96, 256, 0, stream>>>(dstI, bucket_counts, W1, W1p, W2, W2p,
                                              E, nb, nbBin);
    b2_kernel<<<1, 512, 0, stream>>>(bucket_counts, bucket_off, nb);
    b3_kernel<<<nbBin + nbGemm, 256, 0, stream>>>(srcI, dstI, bucket_off, bucket_fill,
                                                  pairs, x, W1p, H1, E, n, nb, nbBin);
    b4_kernel<<<nb, 256, 0, stream>>>(pairs, bucket_off, rowptr, dinv, srcs, n, E, nb);

    agg1_kernel<<<(n + 3) / 4, 256, 0, stream>>>(H1, h1, rowptr, srcs, dinv, bi1, n);
    gemm2_kernel<<<nbGemm, 256, 0, stream>>>(h1, W2p, dinv, H2s, n);
    agg2_kernel<<<(n + 3) / 4, 256, 0, stream>>>(H2s, Zb, rowptr, srcs, dinv, bi2, n);
    mean_kernel<<<1024, 256, 0, stream>>>(Zb, out, n * OUT_DIM, 1.0f / (float)n);
}

// Round 12
// 297.077 us; speedup vs baseline: 2.4281x; 1.1014x over previous
//
#include <hip/hip_runtime.h>
#include <math.h>

#define IN_DIM 128
#define OUT_DIM 64
#define BKT 256      // dst-nodes per bucket
#define CHUNK 4096   // edges per binning block
#define NBMAX 512

typedef __attribute__((ext_vector_type(8))) short short8;
typedef __attribute__((ext_vector_type(4))) float f32x4;
typedef __attribute__((ext_vector_type(2))) float f32x2;

__device__ __forceinline__ ushort f2bf(float f) {
    uint u = __float_as_uint(f);
    u += 0x7FFF + ((u >> 16) & 1);   // round-to-nearest-even
    return (ushort)(u >> 16);
}
__device__ __forceinline__ float bf2f(ushort h) {
    return __uint_as_float(((uint)h) << 16);
}

__device__ __forceinline__ uchar f2fp8(float v) {
    return (uchar)(__builtin_amdgcn_cvt_pk_fp8_f32(v, v, 0, false) & 0xFF);
}

// ---------------- pack W[K=128][N] fp32 -> MFMA B-fragment order bf16 ----------------
__device__ __forceinline__ void packw_body(const float* __restrict__ W, ushort* __restrict__ Bp,
                                           int idx, int N) {
    int e = idx & 7;
    int lane = (idx >> 3) & 63;
    int rest = idx >> 9;
    int nt = rest % (N / 16);
    int kk = rest / (N / 16);
    int k = kk * 32 + (lane >> 4) * 8 + e;
    int n = nt * 16 + (lane & 15);
    Bp[idx] = f2bf(W[k * N + n]);
}

// ---------------- B1: bucket histogram (LDS) || packw1 || packw2 ----------------
__global__ __launch_bounds__(256) void b1_kernel(const int* __restrict__ dst,
                                                 int* __restrict__ bucket_counts,
                                                 const float* __restrict__ W1,
                                                 ushort* __restrict__ W1p,
                                                 const float* __restrict__ W2,
                                                 ushort* __restrict__ W2p,
                                                 int E, int nb, int nbBin) {
    __shared__ int lh[NBMAX];
    int b = blockIdx.x, t = threadIdx.x;
    if (b < nbBin) {
        for (int i = t; i < nb; i += 256) lh[i] = 0;
        __syncthreads();
        int base = b * CHUNK;
#pragma unroll
        for (int i = 0; i < CHUNK / 256; ++i) {
            int e = base + i * 256 + t;
            if (e < E) atomicAdd(&lh[((uint)dst[e]) >> 8], 1);
        }
        __syncthreads();
        for (int i = t; i < nb; i += 256) {
            int c = lh[i];
            if (c) atomicAdd(&bucket_counts[i], c);
        }
    } else if (b < nbBin + 64) {
        packw_body(W1, W1p, (b - nbBin) * 256 + t, 128);      // 128*128
    } else {
        packw_body(W2, W2p, (b - nbBin - 64) * 256 + t, 64);  // 128*64
    }
}

// ---------------- B2: exclusive scan of bucket counts + zero fill/out ----------------
__global__ __launch_bounds__(512) void b2_kernel(const int* __restrict__ bucket_counts,
                                                 int* __restrict__ bucket_off,
                                                 int* __restrict__ bucket_fill,
                                                 float* __restrict__ out, int nb) {
    __shared__ int s[512];
    int t = threadIdx.x;
    if (t < NBMAX) bucket_fill[t] = 0;
    if (t < OUT_DIM) out[t] = 0.0f;
    int v = (t < nb) ? bucket_counts[t] : 0;
    s[t] = v;
    __syncthreads();
    for (int off = 1; off < 512; off <<= 1) {
        int add = (t >= off) ? s[t - off] : 0;
        __syncthreads();
        s[t] += add;
        __syncthreads();
    }
    if (t < nb) bucket_off[t] = s[t] - v;
    if (t == 511) bucket_off[nb] = s[511];   // = E
}

// ---------------- B3: bin scatter (packed pairs) || MFMA gemm1 -> fp8 H1 ----------
__global__ __launch_bounds__(256) void b3_kernel(const int* __restrict__ src,
                                                 const int* __restrict__ dst,
                                                 const int* __restrict__ bucket_off,
                                                 int* __restrict__ bucket_fill,
                                                 uint* __restrict__ pairs,
                                                 const float* __restrict__ X,
                                                 const ushort* __restrict__ Bp,
                                                 uchar* __restrict__ H1,
                                                 int E, int M, int nb, int nbBin) {
    __shared__ int lh[NBMAX];
    __shared__ int lf[NBMAX];
    int b = blockIdx.x, t = threadIdx.x;
    if (b < nbBin) {
        for (int i = t; i < nb; i += 256) lh[i] = 0;
        __syncthreads();
        int base = b * CHUNK;
#pragma unroll
        for (int i = 0; i < CHUNK / 256; ++i) {
            int e = base + i * 256 + t;
            if (e < E) atomicAdd(&lh[((uint)dst[e]) >> 8], 1);
        }
        __syncthreads();
        for (int i = t; i < nb; i += 256) {
            int c = lh[i];
            if (c) lf[i] = bucket_off[i] + atomicAdd(&bucket_fill[i], c);
        }
        __syncthreads();
#pragma unroll
        for (int i = 0; i < CHUNK / 256; ++i) {
            int e = base + i * 256 + t;
            if (e < E) {
                int d = dst[e];
                int r = atomicAdd(&lf[((uint)d) >> 8], 1);
                pairs[r] = (((uint)src[e]) << 8) | ((uint)d & 255);  // src < 2^17
            }
        }
        return;
    }
    // ---- gemm1: H1[M][128] = fp8( X[M][128] @ W1 )  (unscaled; prescaled later in b4) ----
    int wid = t >> 6, lane = t & 63;
    int rowBase = ((b - nbBin) * 4 + wid) * 16;
    if (rowBase >= M) return;
    int m = lane & 15, kg = lane >> 4;
    const float* arow = X + (size_t)(rowBase + m) * 128 + kg * 8;
    short8 af[4];
#pragma unroll
    for (int kk = 0; kk < 4; ++kk) {
        float4 a0 = *(const float4*)(arow + kk * 32);
        float4 a1 = *(const float4*)(arow + kk * 32 + 4);
        short8 v;
        v[0] = (short)f2bf(a0.x); v[1] = (short)f2bf(a0.y);
        v[2] = (short)f2bf(a0.z); v[3] = (short)f2bf(a0.w);
        v[4] = (short)f2bf(a1.x); v[5] = (short)f2bf(a1.y);
        v[6] = (short)f2bf(a1.z); v[7] = (short)f2bf(a1.w);
        af[kk] = v;
    }
#pragma unroll
    for (int nt = 0; nt < 8; ++nt) {
        f32x4 acc = {0.f, 0.f, 0.f, 0.f};
#pragma unroll
        for (int kk = 0; kk < 4; ++kk) {
            short8 bf = *reinterpret_cast<const short8*>(Bp + ((size_t)(kk * 8 + nt) * 64 + lane) * 8);
            acc = __builtin_amdgcn_mfma_f32_16x16x32_bf16(af[kk], bf, acc, 0, 0, 0);
        }
        int col = nt * 16 + m;
#pragma unroll
        for (int r = 0; r < 4; ++r) {
            int row = rowBase + kg * 4 + r;
            H1[(size_t)row * 128 + col] = f2fp8(acc[r]);
        }
    }
}

// ---------------- B4: per-bucket CSR finalize + in-place dinv-prescale of H1 ----------
__global__ __launch_bounds__(256) void b4_kernel(const uint* __restrict__ pairs,
                                                 const int* __restrict__ bucket_off,
                                                 int* __restrict__ rowptr,
                                                 float* __restrict__ dinv,
                                                 int* __restrict__ srcs,
                                                 uchar* __restrict__ H1,
                                                 int n, int E, int nb) {
    __shared__ int lcnt[BKT];
    __shared__ int ls[BKT];
    __shared__ int lfill[BKT];
    __shared__ float sdv[BKT];
    int b = blockIdx.x, t = threadIdx.x;
    int base = b * BKT;
    int bs = min(BKT, n - base);
    int estart = bucket_off[b], eend = bucket_off[b + 1];
    lcnt[t] = 0;
    __syncthreads();
    for (int e = estart + t; e < eend; e += 256)
        atomicAdd(&lcnt[pairs[e] & 255], 1);
    __syncthreads();
    int v = lcnt[t];
    ls[t] = v;
    __syncthreads();
    for (int off = 1; off < 256; off <<= 1) {
        int add = (t >= off) ? ls[t - off] : 0;
        __syncthreads();
        ls[t] += add;
        __syncthreads();
    }
    int excl = ls[t] - v;
    lfill[t] = excl;
    float dvt = rsqrtf((float)(v + 1));   // +1 self loop
    sdv[t] = dvt;
    if (t < bs) {
        rowptr[base + t] = estart + excl;
        dinv[base + t] = dvt;
    }
    if (b == nb - 1 && t == 0) rowptr[n] = E;
    __syncthreads();
    for (int e = estart + t; e < eend; e += 256) {
        uint p = pairs[e];
        int pos = atomicAdd(&lfill[p & 255], 1);
        srcs[estart + pos] = (int)(p >> 8);
    }
    // ---- in-place prescale: H1[base..base+bs) *= dinv[node] (fp8 RMW, exclusive range) ----
    uint* Hrow = (uint*)(H1 + (size_t)base * 128);
    int total_u = bs * 32;                // 32 uints per 128B row
    for (int u = t; u < total_u; u += 256) {
        float s = sdv[u >> 5];
        uint w = Hrow[u];
        f32x2 lo = __builtin_amdgcn_cvt_pk_f32_fp8((int)w, false);
        f32x2 hi = __builtin_amdgcn_cvt_pk_f32_fp8((int)w, true);
        int ow = __builtin_amdgcn_cvt_pk_fp8_f32(lo[0] * s, lo[1] * s, 0, false);
        ow = __builtin_amdgcn_cvt_pk_fp8_f32(hi[0] * s, hi[1] * s, ow, true);
        Hrow[u] = (uint)ow;
    }
}

// ---------------- gemm2: H2[M][64] = fp8( dinv[row] * (h1[M][128] @ W2) ) ------------
__global__ __launch_bounds__(256) void gemm2_kernel(const ushort* __restrict__ A,
                                                    const ushort* __restrict__ Bp,
                                                    const float* __restrict__ dinv,
                                                    uchar* __restrict__ Out, int M) {
    int wid = threadIdx.x >> 6, lane = threadIdx.x & 63;
    int rowBase = (blockIdx.x * 4 + wid) * 16;
    if (rowBase >= M) return;
    int m = lane & 15, kg = lane >> 4;
    const ushort* arow = A + (size_t)(rowBase + m) * 128 + kg * 8;
    short8 af[4];
#pragma unroll
    for (int kk = 0; kk < 4; ++kk)
        af[kk] = *reinterpret_cast<const short8*>(arow + kk * 32);
    float dv[4];
#pragma unroll
    for (int r = 0; r < 4; ++r) dv[r] = dinv[rowBase + kg * 4 + r];
#pragma unroll
    for (int nt = 0; nt < 4; ++nt) {
        f32x4 acc = {0.f, 0.f, 0.f, 0.f};
#pragma unroll
        for (int kk = 0; kk < 4; ++kk) {
            short8 bf = *reinterpret_cast<const short8*>(
                Bp + ((size_t)(kk * 4 + nt) * 64 + lane) * 8);
            acc = __builtin_amdgcn_mfma_f32_16x16x32_bf16(af[kk], bf, acc, 0, 0, 0);
        }
        int col = nt * 16 + m;
#pragma unroll
        for (int r = 0; r < 4; ++r) {
            int row = rowBase + kg * 4 + r;
            Out[(size_t)row * 64 + col] = f2fp8(acc[r] * dv[r]);
        }
    }
}

// ---------------- layer-1 aggregation: half-wave fp8 row gather, relu --------------
// rows prescaled by dinv[src] (b4); 2 edges/VMEM, 8 edges in flight
// h1[v] = relu( dv * ( H1s[v] + sum_s H1s[s] ) + b1 )
__global__ __launch_bounds__(256) void agg1_kernel(const uchar* __restrict__ Hs,
                                                   ushort* __restrict__ Hout,
                                                   const int* __restrict__ rowptr,
                                                   const int* __restrict__ srcs,
                                                   const float* __restrict__ dinv,
                                                   const float* __restrict__ bias, int n) {
    int wv = __builtin_amdgcn_readfirstlane(threadIdx.x) >> 6;
    int lane = threadIdx.x & 63;
    int node = blockIdx.x * 4 + wv;
    if (node >= n) return;
    int h = lane >> 5, c = lane & 31;
    float dv = dinv[node];
    int start = rowptr[node], end = rowptr[node + 1];
    float a0 = 0.f, a1 = 0.f, a2 = 0.f, a3 = 0.f;
    if (h == 0) {
        uint s = ((const uint*)(Hs + (size_t)node * 128))[c];
        f32x2 lo = __builtin_amdgcn_cvt_pk_f32_fp8((int)s, false);
        f32x2 hi = __builtin_amdgcn_cvt_pk_f32_fp8((int)s, true);
        a0 = lo[0]; a1 = lo[1]; a2 = hi[0]; a3 = hi[1];
    }
    for (int j = start; j < end; j += 8) {
#pragma unroll
        for (int i = 0; i < 4; ++i) {
            int jj = j + 2 * i + h;
            int sj = srcs[min(jj, end - 1)];
            float w = (jj < end) ? 1.0f : 0.0f;
            uint v = ((const uint*)(Hs + (size_t)sj * 128))[c];
            f32x2 lo = __builtin_amdgcn_cvt_pk_f32_fp8((int)v, false);
            f32x2 hi = __builtin_amdgcn_cvt_pk_f32_fp8((int)v, true);
            a0 = fmaf(w, lo[0], a0);
            a1 = fmaf(w, lo[1], a1);
            a2 = fmaf(w, hi[0], a2);
            a3 = fmaf(w, hi[1], a3);
        }
    }
    a0 += __shfl_xor(a0, 32);
    a1 += __shfl_xor(a1, 32);
    a2 += __shfl_xor(a2, 32);
    a3 += __shfl_xor(a3, 32);
    if (h == 0) {
        float4 bv = *(const float4*)(bias + 4 * c);
        float o0 = fmaxf(fmaf(a0, dv, bv.x), 0.f);
        float o1 = fmaxf(fmaf(a1, dv, bv.y), 0.f);
        float o2 = fmaxf(fmaf(a2, dv, bv.z), 0.f);
        float o3 = fmaxf(fmaf(a3, dv, bv.w), 0.f);
        uint2 o;
        o.x = (uint)f2bf(o0) | ((uint)f2bf(o1) << 16);
        o.y = (uint)f2bf(o2) | ((uint)f2bf(o3) << 16);
        ((uint2*)(Hout + (size_t)node * 128))[c] = o;
    }
}

// ---------------- layer-2 aggregation: quarter-wave fp8 gather, sigmoid ------------
__global__ __launch_bounds__(256) void agg2_kernel(const uchar* __restrict__ Hs,
                                                   ushort* __restrict__ Z,
                                                   const int* __restrict__ rowptr,
                                                   const int* __restrict__ srcs,
                                                   const float* __restrict__ dinv,
                                                   const float* __restrict__ bias, int n) {
    int wv = __builtin_amdgcn_readfirstlane(threadIdx.x) >> 6;
    int lane = threadIdx.x & 63;
    int node = blockIdx.x * 4 + wv;
    if (node >= n) return;
    int q = lane >> 4, c = lane & 15;
    float dv = dinv[node];
    int start = rowptr[node], end = rowptr[node + 1];
    float a0 = 0.f, a1 = 0.f, a2 = 0.f, a3 = 0.f;
    if (q == 0) {
        uint s = ((const uint*)(Hs + (size_t)node * 64))[c];
        f32x2 lo = __builtin_amdgcn_cvt_pk_f32_fp8((int)s, false);
        f32x2 hi = __builtin_amdgcn_cvt_pk_f32_fp8((int)s, true);
        a0 = lo[0]; a1 = lo[1]; a2 = hi[0]; a3 = hi[1];
    }
    for (int j = start; j < end; j += 16) {
#pragma unroll
        for (int i = 0; i < 4; ++i) {
            int jj = j + 4 * i + q;
            int sj = srcs[min(jj, end - 1)];
            float w = (jj < end) ? 1.0f : 0.0f;
            uint v = ((const uint*)(Hs + (size_t)sj * 64))[c];
            f32x2 lo = __builtin_amdgcn_cvt_pk_f32_fp8((int)v, false);
            f32x2 hi = __builtin_amdgcn_cvt_pk_f32_fp8((int)v, true);
            a0 = fmaf(w, lo[0], a0);
            a1 = fmaf(w, lo[1], a1);
            a2 = fmaf(w, hi[0], a2);
            a3 = fmaf(w, hi[1], a3);
        }
    }
#pragma unroll
    for (int d = 16; d <= 32; d <<= 1) {
        a0 += __shfl_xor(a0, d);
        a1 += __shfl_xor(a1, d);
        a2 += __shfl_xor(a2, d);
        a3 += __shfl_xor(a3, d);
    }
    if (q == 0) {
        float4 bv = *(const float4*)(bias + 4 * c);
        float z0 = 1.0f / (1.0f + __expf(-fmaf(a0, dv, bv.x)));
        float z1 = 1.0f / (1.0f + __expf(-fmaf(a1, dv, bv.y)));
        float z2 = 1.0f / (1.0f + __expf(-fmaf(a2, dv, bv.z)));
        float z3 = 1.0f / (1.0f + __expf(-fmaf(a3, dv, bv.w)));
        uint2 o;
        o.x = (uint)f2bf(z0) | ((uint)f2bf(z1) << 16);
        o.y = (uint)f2bf(z2) | ((uint)f2bf(z3) << 16);
        ((uint2*)(Z + (size_t)node * 64))[c] = o;
    }
}

// ---------------- column mean over bf16 Z[n][64] ----------------
__global__ __launch_bounds__(256) void mean_kernel(const ushort* __restrict__ Z,
                                                   float* __restrict__ out,
                                                   int total, float inv_n) {
    __shared__ float s[256];
    int t = threadIdx.x;
    float acc = 0.0f;
    for (int i = blockIdx.x * 256 + t; i < total; i += gridDim.x * 256) acc += bf2f(Z[i]);
    s[t] = acc;
    __syncthreads();
    if (t < 64) {
        atomicAdd(&out[t], (s[t] + s[t + 64] + s[t + 128] + s[t + 192]) * inv_n);
    }
}

// ---------------- launch ----------------
extern "C" void kernel_launch(void* const* d_in, const int* in_sizes, int n_in,
                              void* d_out, int out_size, void* d_ws, size_t ws_size,
                              hipStream_t stream) {
    const float* x   = (const float*)d_in[0];
    const int*   ei  = (const int*)d_in[1];
    const float* W1  = (const float*)d_in[2];
    const float* bi1 = (const float*)d_in[3];
    const float* W2  = (const float*)d_in[4];
    const float* bi2 = (const float*)d_in[5];
    float* out = (float*)d_out;

    const int n = in_sizes[0] / IN_DIM;   // 100000
    const int E = in_sizes[1] / 2;        // 1600000
    const int* srcI = ei;
    const int* dstI = ei + E;

    // workspace carve (256B aligned)
    char* ws = (char*)d_ws;
    size_t off = 0;
    auto carve = [&](size_t bytes) {
        void* p = ws + off;
        off = (off + bytes + 255) & ~(size_t)255;
        return p;
    };
    int*    bucket_counts = (int*)carve(NBMAX * 4);
    int*    bucket_fill   = (int*)carve(NBMAX * 4);
    int*    bucket_off    = (int*)carve((NBMAX + 1) * 4);
    int*    rowptr        = (int*)carve(((size_t)n + 1) * 4);
    float*  dinv          = (float*)carve((size_t)n * 4);
    int*    srcs          = (int*)carve((size_t)E * 4);
    uint*   pairs         = (uint*)carve((size_t)E * 4);
    ushort* W1p           = (ushort*)carve(128 * 128 * 2);
    ushort* W2p           = (ushort*)carve(128 * 64 * 2);
    uchar*  H1            = (uchar*)carve((size_t)n * 128);      // fp8 X@W1, prescaled in b4
    ushort* h1            = (ushort*)carve((size_t)n * 128 * 2); // bf16 relu output
    uchar*  H2s           = (uchar*)carve((size_t)n * 64);       // fp8, prescaled h1@W2
    ushort* Zb            = (ushort*)carve((size_t)n * 64 * 2);  // bf16 sigmoid output

    const int nb     = (n + BKT - 1) / BKT;        // 391 buckets
    const int nbBin  = (E + CHUNK - 1) / CHUNK;    // 391 binning blocks
    const int nbGemm = (n / 16 + 3) / 4;           // 1563

    hipMemsetAsync(bucket_counts, 0, NBMAX * 4, stream);

    b1_kernel<<<nbBin + 96, 256, 0, stream>>>(dstI, bucket_counts, W1, W1p, W2, W2p,
                                              E, nb, nbBin);
    b2_kernel<<<1, 512, 0, stream>>>(bucket_counts, bucket_off, bucket_fill, out, nb);
    b3_kernel<<<nbBin + nbGemm, 256, 0, stream>>>(srcI, dstI, bucket_off, bucket_fill,
                                                  pairs, x, W1p, H1, E, n, nb, nbBin);
    b4_kernel<<<nb, 256, 0, stream>>>(pairs, bucket_off, rowptr, dinv, srcs, H1, n, E, nb);

    agg1_kernel<<<(n + 3) / 4, 256, 0, stream>>>(H1, h1, rowptr, srcs, dinv, bi1, n);
    gemm2_kernel<<<nbGemm, 256, 0, stream>>>(h1, W2p, dinv, H2s, n);
    agg2_kernel<<<(n + 3) / 4, 256, 0, stream>>>(H2s, Zb, rowptr, srcs, dinv, bi2, n);
    mean_kernel<<<1024, 256, 0, stream>>>(Zb, out, n * OUT_DIM, 1.0f / (float)n);
}